// Round 1
// baseline (671.847 us; speedup 1.0000x reference)
//
#include <hip/hip_runtime.h>

#define N_USERS 100000
#define N_ITEMS 50000
#define N_NODES 150000
#define D 64
#define NNZ 2000000
#define BATCH 256
#define POP_BINS 10

// bucketed CSR params
#define BSH 9
#define NB2 293            // ceil(150000/512)
#define CAP 8192           // max edges per bucket (mean 6827, sigma ~82)
#define P1_EPB 4096        // edges per block in pass 1
#define P1_BLOCKS 489      // ceil(NNZ/P1_EPB)

#define ST_P 130           // I-tile LDS pad for transposed stages

// ---------------- bucket count: LDS histogram -> global ----------------------
__global__ __launch_bounds__(256) void k_bcount(const int* __restrict__ rows,
                                                int* __restrict__ bcnt) {
  __shared__ int c[NB2];
  int t = threadIdx.x;
  for (int i = t; i < NB2; i += 256) c[i] = 0;
  __syncthreads();
  int base = blockIdx.x * P1_EPB;
  for (int i = 0; i < 16; i++) {
    int e = base + i * 256 + t;
    if (e < NNZ) atomicAdd(&c[rows[e] >> BSH], 1);
  }
  __syncthreads();
  for (int i = t; i < NB2; i += 256)
    if (c[i]) atomicAdd(&bcnt[i], c[i]);
}

// ---------------- bucket scan: exclusive, in-place (becomes bcur) ------------
__global__ __launch_bounds__(512) void k_bscan(int* __restrict__ bcnt) {
  __shared__ int s[512];
  int t = threadIdx.x;
  int v = (t < NB2) ? bcnt[t] : 0;
  s[t] = v;
  __syncthreads();
  for (int o = 1; o < 512; o <<= 1) {
    int x = (t >= o) ? s[t - o] : 0;
    __syncthreads();
    s[t] += x;
    __syncthreads();
  }
  if (t < NB2) bcnt[t] = s[t] - v;  // exclusive base; p1 advances to inclusive
}

// ---------------- pass 1: bucket edges, TWO-PASS (no per-thread arrays) -----
__global__ __launch_bounds__(256) void k_p1(const int* __restrict__ rows,
                                            const int* __restrict__ cols,
                                            const float* __restrict__ vals,
                                            int* __restrict__ bcur,
                                            uint2* __restrict__ gstage) {
  __shared__ int cnt[NB2];
  __shared__ int gbase[NB2];
  int t = threadIdx.x;
  for (int i = t; i < NB2; i += 256) cnt[i] = 0;
  __syncthreads();
  int base = blockIdx.x * P1_EPB;
  // pass A: count buckets
  for (int i = 0; i < 16; i++) {
    int e = base + i * 256 + t;
    if (e < NNZ) atomicAdd(&cnt[rows[e] >> BSH], 1);
  }
  __syncthreads();
  for (int i = t; i < NB2; i += 256) {
    int c = cnt[i];
    gbase[i] = c ? atomicAdd(&bcur[i], c) : 0;
    cnt[i] = 0;
  }
  __syncthreads();
  // pass B: re-read (L2-hot) and scatter clustered
  for (int i = 0; i < 16; i++) {
    int e = base + i * 256 + t;
    if (e < NNZ) {
      int r = rows[e];
      int b = r >> BSH;
      int rank = atomicAdd(&cnt[b], 1);
      unsigned key = ((unsigned)(r & 511) << 18) | (unsigned)cols[e];
      gstage[gbase[b] + rank] = make_uint2(key, __float_as_uint(vals[e]));
    }
  }
}

// ---------------- pass 2: per-bucket LDS counting sort, contiguous writes ---
// Also produces rowptr (bucketbase + local exclusive scan).
__global__ __launch_bounds__(256) void k_p2(const int* __restrict__ bcur,
                                            const uint2* __restrict__ gstage,
                                            uint2* __restrict__ epack,
                                            int* __restrict__ rowptr) {
  __shared__ int cnt[512];
  __shared__ int off[512];
  __shared__ int s[256];
  __shared__ uint2 buf[CAP];
  int b = blockIdx.x, t = threadIdx.x;
  int base = (b == 0) ? 0 : bcur[b - 1];  // post-p1 bcur = inclusive scan
  int end = bcur[b];
  int n = end - base;
  cnt[t] = 0;
  cnt[t + 256] = 0;
  __syncthreads();
  for (int j = t; j < n; j += 256)
    atomicAdd(&cnt[gstage[base + j].x >> 18], 1);
  __syncthreads();
  // scan 512 entries (each thread owns 2)
  int c0 = cnt[2 * t], c1 = cnt[2 * t + 1];
  s[t] = c0 + c1;
  __syncthreads();
  for (int o = 1; o < 256; o <<= 1) {
    int x = (t >= o) ? s[t - o] : 0;
    __syncthreads();
    s[t] += x;
    __syncthreads();
  }
  int ex = t ? s[t - 1] : 0;
  off[2 * t] = ex;
  off[2 * t + 1] = ex + c0;
  int gr = (b << BSH) + 2 * t;
  if (gr < N_NODES) rowptr[gr] = base + ex;
  if (gr + 1 < N_NODES) rowptr[gr + 1] = base + ex + c0;
  if (b == NB2 - 1 && t == 0) rowptr[N_NODES] = NNZ;
  __syncthreads();
  for (int j = t; j < n; j += 256) {
    uint2 ed = gstage[base + j];
    int lr = ed.x >> 18;
    int pos = atomicAdd(&off[lr], 1);
    buf[pos] = make_uint2(ed.x & 0x3FFFFu, ed.y);
  }
  __syncthreads();
  for (int j = t; j < n; j += 256) epack[base + j] = buf[j];
}

// ---------------- SPMM layer 1: gather from emb directly, init Oacc ---------
// Restructured: all descriptors for the row are issued up front (wave-uniform
// scalar loads), then gathers go out in unrolled chunks of 16 with clamped
// dummy indices (val=0, address = last real edge -> L1-hot, no extra fetch).
// Critical path per row: 1 descriptor latency + 1 gather latency, with up to
// 16 gathers in flight per wave (was ~3.3 serialized pairs, 4 in flight).
__global__ __launch_bounds__(256) void k_spmm1(const int* __restrict__ rowptr,
                                               const uint2* __restrict__ epack,
                                               const float* __restrict__ ue,
                                               const float* __restrict__ ie,
                                               float* __restrict__ Eout,
                                               float* __restrict__ Oacc) {
  int wave = blockIdx.x * 4 + (threadIdx.x >> 6);
  int row = __builtin_amdgcn_readfirstlane(wave);
  if (row >= N_NODES) return;
  int lane = threadIdx.x & 63;
  int beg = rowptr[row];
  int end = rowptr[row + 1];
  int n = end - beg;
  const uint2* ep = epack + beg;
  float acc = 0.f;
  int nn = n > 64 ? 64 : n;
  for (int j0 = 0; j0 < nn; j0 += 16) {
    float pv[16];
#pragma unroll
    for (int u = 0; u < 16; u++) {
      int j = j0 + u;
      int jc = (j < nn) ? j : (nn - 1);          // clamp: dummy hits hot line
      uint2 e = ep[jc];
      float val = (j < nn) ? __uint_as_float(e.y) : 0.f;
      int c = (int)e.x;
      const float* src = (c < N_USERS) ? ue + (size_t)c * D
                                       : ie + (size_t)(c - N_USERS) * D;
      pv[u] = val * src[lane];
    }
#pragma unroll
    for (int u = 0; u < 16; u++) acc += pv[u];   // in vmcnt return order
  }
  for (int j = 64; j < n; ++j) {                 // (astronomically rare) tail
    uint2 e0 = ep[j];
    int c0 = (int)e0.x;
    const float* s0 = (c0 < N_USERS) ? ue + (size_t)c0 * D
                                     : ie + (size_t)(c0 - N_USERS) * D;
    acc += __uint_as_float(e0.y) * s0[lane];
  }
  float e = (row < N_USERS) ? ue[(size_t)row * D + lane]
                            : ie[(size_t)(row - N_USERS) * D + lane];
  int o = row * D + lane;
  Eout[o] = acc;
  Oacc[o] = 0.25f * (e + acc);
}

// ---------------- SPMM layers 2,3 (Eout==nullptr on the last layer) ---------
__global__ __launch_bounds__(256) void k_spmm(const int* __restrict__ rowptr,
                                              const uint2* __restrict__ epack,
                                              const float* __restrict__ Ein,
                                              float* __restrict__ Eout,
                                              float* __restrict__ Oacc) {
  int wave = blockIdx.x * 4 + (threadIdx.x >> 6);
  int row = __builtin_amdgcn_readfirstlane(wave);
  if (row >= N_NODES) return;
  int lane = threadIdx.x & 63;
  int beg = rowptr[row];
  int end = rowptr[row + 1];
  int n = end - beg;
  const uint2* ep = epack + beg;
  float acc = 0.f;
  int nn = n > 64 ? 64 : n;
  for (int j0 = 0; j0 < nn; j0 += 16) {
    float pv[16];
#pragma unroll
    for (int u = 0; u < 16; u++) {
      int j = j0 + u;
      int jc = (j < nn) ? j : (nn - 1);
      uint2 e = ep[jc];
      float val = (j < nn) ? __uint_as_float(e.y) : 0.f;
      pv[u] = val * Ein[(size_t)e.x * D + lane];
    }
#pragma unroll
    for (int u = 0; u < 16; u++) acc += pv[u];
  }
  for (int j = 64; j < n; ++j) {
    uint2 e0 = ep[j];
    acc += __uint_as_float(e0.y) * Ein[(size_t)e0.x * D + lane];
  }
  int o = row * D + lane;
  if (Eout) Eout[o] = acc;
  Oacc[o] += 0.25f * acc;
}

// ---------------- weight transpose: uW1T[64][64] (for k_user) ---------------
__global__ __launch_bounds__(256) void k_wt(const float* __restrict__ uW1,
                                            float* __restrict__ WT) {
  int t = blockIdx.x * 256 + threadIdx.x;
  if (t < 4096) {
    int o = t >> 6, k = t & 63;
    WT[t] = uW1[k * 64 + o];
  }
}

// ---------------- pop-row precompute: hp[b]=p_b@gW1_p, pp1[b]=p_b@iW1 -------
__global__ __launch_bounds__(256) void k_pw(const float* __restrict__ pop,
                                            const float* __restrict__ gW1,
                                            const float* __restrict__ iW1,
                                            float* __restrict__ hp,
                                            float* __restrict__ pp1) {
  for (int idx = threadIdx.x; idx < 2 * POP_BINS * 64; idx += 256) {
    int q = idx;
    bool second = q >= POP_BINS * 64;
    if (second) q -= POP_BINS * 64;
    int b = q >> 6, o = q & 63;
    float s = 0.f;
    if (!second) {
      for (int k = 0; k < 64; k++) s += pop[b * 64 + k] * gW1[(64 + k) * 64 + o];
      hp[q] = s;
    } else {
      for (int k = 0; k < 64; k++) s += pop[b * 64 + k] * iW1[k * 64 + o];
      pp1[q] = s;
    }
  }
}

// ---------------- user MLP: thread per user, scalar weights, write U^T ------
__global__ __launch_bounds__(64) void k_user(const float* __restrict__ Oacc,
                                             const int* __restrict__ users,
                                             const float* __restrict__ ubias,
                                             const float* __restrict__ uW1T,
                                             const float* __restrict__ ub1,
                                             const float* __restrict__ uW2,
                                             const float* __restrict__ ub2,
                                             float* __restrict__ Ut) {
  int b = blockIdx.x * 64 + threadIdx.x;
  int u = users[b];
  float x[64];
  const float4* xr = (const float4*)(Oacc + (size_t)u * 64);
#pragma unroll
  for (int q = 0; q < 16; q++) {
    float4 t4 = xr[q];
    x[4 * q] = t4.x; x[4 * q + 1] = t4.y; x[4 * q + 2] = t4.z; x[4 * q + 3] = t4.w;
  }
  float acc[64];
#pragma unroll
  for (int o2 = 0; o2 < 64; o2++) acc[o2] = ub2[o2];
#pragma unroll 1
  for (int o = 0; o < 64; o++) {
    const float* w = uW1T + o * 64;
    float a0 = ub1[o], a1 = 0.f, a2 = 0.f, a3 = 0.f;
#pragma unroll
    for (int k = 0; k < 64; k += 4) {
      a0 += x[k] * w[k]; a1 += x[k + 1] * w[k + 1];
      a2 += x[k + 2] * w[k + 2]; a3 += x[k + 3] * w[k + 3];
    }
    float hv = a0 + a1 + a2 + a3;
    hv = hv > 0.f ? hv : 0.f;
    const float* w2 = uW2 + o * 64;
#pragma unroll
    for (int o2 = 0; o2 < 64; o2++) acc[o2] += hv * w2[o2];
  }
#pragma unroll 1
  for (int o2 = 0; o2 < 64; o2++) Ut[o2 * 256 + b] = acc[o2];
  Ut[64 * 256 + b] = ubias[u];  // BIAS_SCALE = 1.0
}

// ---------------- GEMM1 fused with gate (was k_gemm1 + k_zf) -----------------
// Computes G|T = X @ [gW1_x | iW1] in registers, then the z-reduction through
// LDS and H1 = relu((1-z)*T + z*pp1 + ib1) written directly. Saves the
// G/T round-trip (51 MB of traffic) and a 12500-block launch.
__global__ __launch_bounds__(256) void k_gemm1z(const float* __restrict__ Oacc,
                                                const float* __restrict__ gW1,
                                                const float* __restrict__ iW1,
                                                const int* __restrict__ bins,
                                                const float* __restrict__ hp,
                                                const float* __restrict__ pp1,
                                                const float* __restrict__ gb1,
                                                const float* __restrict__ gW2,
                                                const float* __restrict__ gb2,
                                                const float* __restrict__ ib1,
                                                float* __restrict__ H1) {
  __shared__ float Is[64 * ST_P];
  __shared__ float Bs[64 * 128];
  __shared__ float zp[128][9];   // z partials, padded
  __shared__ float zs[128];      // final z per item
  int tid = threadIdx.x;
  int i0 = blockIdx.x * 128;
  {
    int c4 = tid & 15, r0 = tid >> 4;
#pragma unroll
    for (int s = 0; s < 8; s++) {
      int r = r0 + s * 16;
      int it = i0 + r;
      float4 v = make_float4(0.f, 0.f, 0.f, 0.f);
      if (it < N_ITEMS) v = *(const float4*)(Oacc + (size_t)(N_USERS + it) * 64 + c4 * 4);
      Is[(c4 * 4 + 0) * ST_P + r] = v.x;
      Is[(c4 * 4 + 1) * ST_P + r] = v.y;
      Is[(c4 * 4 + 2) * ST_P + r] = v.z;
      Is[(c4 * 4 + 3) * ST_P + r] = v.w;
    }
  }
  for (int idx = tid; idx < 64 * 128; idx += 256) {
    int k = idx >> 7, o = idx & 127;
    Bs[idx] = (o < 64) ? gW1[k * 64 + o] : iW1[k * 64 + (o - 64)];
  }
  __syncthreads();
  int tx = tid & 15, ty = tid >> 4;
  float acc[8][8];
#pragma unroll
  for (int a = 0; a < 8; a++)
#pragma unroll
    for (int b = 0; b < 8; b++) acc[a][b] = 0.f;
  const float* ip = Is + tx * 8;
  const float* wp = Bs + ty * 8;
#pragma unroll 2
  for (int k = 0; k < 64; k++) {
    float4 iv0 = *(const float4*)(ip + k * ST_P);
    float4 iv1 = *(const float4*)(ip + k * ST_P + 4);
    float4 wv0 = *(const float4*)(wp + k * 128);
    float4 wv1 = *(const float4*)(wp + k * 128 + 4);
    float iv[8] = {iv0.x, iv0.y, iv0.z, iv0.w, iv1.x, iv1.y, iv1.z, iv1.w};
    float wv[8] = {wv0.x, wv0.y, wv0.z, wv0.w, wv1.x, wv1.y, wv1.z, wv1.w};
#pragma unroll
    for (int a = 0; a < 8; a++)
#pragma unroll
      for (int b = 0; b < 8; b++) acc[a][b] += iv[a] * wv[b];
  }
  int ibase = i0 + tx * 8;
  // --- gate epilogue ---
  if (ty < 8) {  // G half: z partials over this thread's 8 o-columns
    int o0 = ty * 8;
#pragma unroll
    for (int a = 0; a < 8; a++) {
      int it = ibase + a;
      float p = 0.f;
      if (it < N_ITEMS) {
        int bin = bins[it];
        const float* hpr = hp + bin * 64 + o0;
#pragma unroll
        for (int b = 0; b < 8; b++) {
          float g = acc[a][b] + hpr[b] + gb1[o0 + b];
          g = g > 0.f ? g : 0.f;
          p += g * gW2[o0 + b];
        }
      }
      zp[tx * 8 + a][ty] = p;
    }
  }
  __syncthreads();
  if (tid < 128) {
    float s = gb2[0];
#pragma unroll
    for (int k = 0; k < 8; k++) s += zp[tid][k];
    zs[tid] = 1.f / (1.f + expf(-s));
  }
  __syncthreads();
  if (ty >= 8) {  // T half: fuse + relu -> H1
    int o0 = (ty - 8) * 8;
#pragma unroll
    for (int a = 0; a < 8; a++) {
      int it = ibase + a;
      if (it < N_ITEMS) {
        float z = zs[tx * 8 + a];
        int bin = bins[it];
        const float* ppr = pp1 + bin * 64 + o0;
        float h[8];
#pragma unroll
        for (int b = 0; b < 8; b++) {
          float v = (1.f - z) * acc[a][b] + z * ppr[b] + ib1[o0 + b];
          h[b] = v > 0.f ? v : 0.f;
        }
        *(float4*)(H1 + (size_t)it * 64 + o0) = make_float4(h[0], h[1], h[2], h[3]);
        *(float4*)(H1 + (size_t)it * 64 + o0 + 4) = make_float4(h[4], h[5], h[6], h[7]);
      }
    }
  }
}

// ---------------- GEMM2: I = H1 @ iW2 + ib2  (128x64 tile, K=64) ------------
__global__ __launch_bounds__(256) void k_gemm2(const float* __restrict__ H1,
                                               const float* __restrict__ iW2,
                                               const float* __restrict__ ib2,
                                               float* __restrict__ I) {
  __shared__ float Is[64 * ST_P];
  __shared__ float Bs[64 * 64];
  int tid = threadIdx.x;
  int i0 = blockIdx.x * 128;
  {
    int c4 = tid & 15, r0 = tid >> 4;
#pragma unroll
    for (int s = 0; s < 8; s++) {
      int r = r0 + s * 16;
      int it = i0 + r;
      float4 v = make_float4(0.f, 0.f, 0.f, 0.f);
      if (it < N_ITEMS) v = *(const float4*)(H1 + (size_t)it * 64 + c4 * 4);
      Is[(c4 * 4 + 0) * ST_P + r] = v.x;
      Is[(c4 * 4 + 1) * ST_P + r] = v.y;
      Is[(c4 * 4 + 2) * ST_P + r] = v.z;
      Is[(c4 * 4 + 3) * ST_P + r] = v.w;
    }
  }
  for (int idx = tid; idx < 64 * 64; idx += 256) Bs[idx] = iW2[idx];
  __syncthreads();
  int tx = tid & 15, ty = tid >> 4;
  float acc[8][4];
#pragma unroll
  for (int a = 0; a < 8; a++)
#pragma unroll
    for (int b = 0; b < 4; b++) acc[a][b] = 0.f;
  const float* ip = Is + tx * 8;
  const float* wp = Bs + ty * 4;
#pragma unroll 2
  for (int k = 0; k < 64; k++) {
    float4 iv0 = *(const float4*)(ip + k * ST_P);
    float4 iv1 = *(const float4*)(ip + k * ST_P + 4);
    float4 wv = *(const float4*)(wp + k * 64);
    float iv[8] = {iv0.x, iv0.y, iv0.z, iv0.w, iv1.x, iv1.y, iv1.z, iv1.w};
    float wvv[4] = {wv.x, wv.y, wv.z, wv.w};
#pragma unroll
    for (int a = 0; a < 8; a++)
#pragma unroll
      for (int b = 0; b < 4; b++) acc[a][b] += iv[a] * wvv[b];
  }
  int ibase = i0 + tx * 8;
  int oc = ty * 4;
  float b0 = ib2[oc], b1 = ib2[oc + 1], b2 = ib2[oc + 2], b3 = ib2[oc + 3];
#pragma unroll
  for (int a = 0; a < 8; a++) {
    int it = ibase + a;
    if (it < N_ITEMS) {
      float4 s0 = make_float4(acc[a][0] + b0, acc[a][1] + b1,
                              acc[a][2] + b2, acc[a][3] + b3);
      *(float4*)(I + (size_t)it * 64 + oc) = s0;
    }
  }
}

// ---------------- scores: 128x128 tile GEMM, 8x8 register blocking ----------
__global__ __launch_bounds__(256) void k_scores(const float* __restrict__ I,
                                                const float* __restrict__ Ut,
                                                const float* __restrict__ item_bias,
                                                float* __restrict__ out) {
  __shared__ float Is[64 * ST_P];
  __shared__ float Us[64 * 128];
  int tid = threadIdx.x;
  int i0 = blockIdx.x * 128;
  int ubase = blockIdx.y * 128;
  {
    int c4 = tid & 15, r0 = tid >> 4;
#pragma unroll
    for (int s = 0; s < 8; s++) {
      int r = r0 + s * 16;
      int it = i0 + r;
      float4 v = make_float4(0.f, 0.f, 0.f, 0.f);
      if (it < N_ITEMS) v = *(const float4*)(I + (size_t)it * 64 + c4 * 4);
      Is[(c4 * 4 + 0) * ST_P + r] = v.x;
      Is[(c4 * 4 + 1) * ST_P + r] = v.y;
      Is[(c4 * 4 + 2) * ST_P + r] = v.z;
      Is[(c4 * 4 + 3) * ST_P + r] = v.w;
    }
  }
  {
    int u4 = tid & 31, k0 = tid >> 5;
#pragma unroll
    for (int s = 0; s < 8; s++) {
      int k = k0 + s * 8;
      float4 v = *(const float4*)(Ut + k * 256 + ubase + u4 * 4);
      *(float4*)(Us + k * 128 + u4 * 4) = v;
    }
  }
  __syncthreads();
  int tx = tid & 15;
  int ty = tid >> 4;
  float acc[8][8];
#pragma unroll
  for (int a = 0; a < 8; a++)
#pragma unroll
    for (int b = 0; b < 8; b++) acc[a][b] = 0.f;
  const float* ip = Is + tx * 8;
  const float* up = Us + ty * 8;
#pragma unroll 2
  for (int k = 0; k < 64; k++) {
    float4 iv0 = *(const float4*)(ip + k * ST_P);
    float4 iv1 = *(const float4*)(ip + k * ST_P + 4);
    float4 uv0 = *(const float4*)(up + k * 128);
    float4 uv1 = *(const float4*)(up + k * 128 + 4);
    float iv[8] = {iv0.x, iv0.y, iv0.z, iv0.w, iv1.x, iv1.y, iv1.z, iv1.w};
    float uv[8] = {uv0.x, uv0.y, uv0.z, uv0.w, uv1.x, uv1.y, uv1.z, uv1.w};
#pragma unroll
    for (int a = 0; a < 8; a++)
#pragma unroll
      for (int b = 0; b < 8; b++) acc[a][b] += iv[a] * uv[b];
  }
  int ibase = i0 + tx * 8;
  float ib[8];
#pragma unroll
  for (int a = 0; a < 8; a++)
    ib[a] = (ibase + a < N_ITEMS) ? item_bias[ibase + a] : 0.f;
#pragma unroll
  for (int bb = 0; bb < 8; bb++) {
    int bu = ubase + ty * 8 + bb;
    float ubias = Ut[64 * 256 + bu];
    float* orow = out + (size_t)bu * N_ITEMS + ibase;
    if (ibase + 7 < N_ITEMS) {
      float4 s0 = make_float4(acc[0][bb] + ubias + ib[0], acc[1][bb] + ubias + ib[1],
                              acc[2][bb] + ubias + ib[2], acc[3][bb] + ubias + ib[3]);
      float4 s1 = make_float4(acc[4][bb] + ubias + ib[4], acc[5][bb] + ubias + ib[5],
                              acc[6][bb] + ubias + ib[6], acc[7][bb] + ubias + ib[7]);
      *(float4*)orow = s0;
      *(float4*)(orow + 4) = s1;
    } else {
#pragma unroll
      for (int a = 0; a < 8; a++)
        if (ibase + a < N_ITEMS) orow[a] = acc[a][bb] + ubias + ib[a];
    }
  }
}

extern "C" void kernel_launch(void* const* d_in, const int* in_sizes, int n_in,
                              void* d_out, int out_size, void* d_ws, size_t ws_size,
                              hipStream_t stream) {
  const float* user_emb  = (const float*)d_in[0];
  const float* item_emb  = (const float*)d_in[1];
  const float* user_bias = (const float*)d_in[2];
  const float* item_bias = (const float*)d_in[3];
  const float* pop_emb   = (const float*)d_in[4];
  const float* uW1 = (const float*)d_in[5];
  const float* ub1 = (const float*)d_in[6];
  const float* uW2 = (const float*)d_in[7];
  const float* ub2 = (const float*)d_in[8];
  const float* iW1 = (const float*)d_in[9];
  const float* ib1 = (const float*)d_in[10];
  const float* iW2 = (const float*)d_in[11];
  const float* ib2 = (const float*)d_in[12];
  const float* gW1 = (const float*)d_in[13];
  const float* gb1 = (const float*)d_in[14];
  const float* gW2 = (const float*)d_in[15];
  const float* gb2 = (const float*)d_in[16];
  const float* adj_vals = (const float*)d_in[17];
  const int* adj_rows = (const int*)d_in[18];
  const int* adj_cols = (const int*)d_in[19];
  const int* bins  = (const int*)d_in[20];
  const int* users = (const int*)d_in[21];
  float* out = (float*)d_out;

  // workspace layout (float offsets); total ~132.7 MB
  float* ws = (float*)d_ws;
  float* Oacc = ws;                    // 9,600,000
  float* bufA = ws + 9600000;          // 9,600,000 (E2/H1 region)
  float* bufB = ws + 19200000;         // 9,600,000 (gstage pre-spmm; E1; I after)
  uint2* epack = (uint2*)(ws + 28800000);      // 2,000,000 * 8B
  int* rowptr = (int*)(ws + 32800000);         // 150,001
  float* Ut   = ws + 33130000;                 // 65*256
  float* WT   = ws + 33150000;                 // 4,096 (uW1T)
  float* hp   = ws + 33160000;                 // 640
  float* pp1  = ws + 33161000;                 // 640
  int* bcur   = (int*)(ws + 33170000);         // 293 (bcnt -> excl scan -> cursor)
  uint2* gstage = (uint2*)bufB;
  float* H1 = bufA + 6400000;                  // 3,200,000
  float* I  = bufB;                            // 3,200,000
  const float* uW1T = WT;

  hipMemsetAsync(bcur, 0, NB2 * sizeof(int), stream);
  k_bcount<<<P1_BLOCKS, 256, 0, stream>>>(adj_rows, bcur);
  k_bscan<<<1, 512, 0, stream>>>(bcur);
  k_p1<<<P1_BLOCKS, 256, 0, stream>>>(adj_rows, adj_cols, adj_vals, bcur, gstage);
  k_p2<<<NB2, 256, 0, stream>>>(bcur, gstage, epack, rowptr);

  k_spmm1<<<37500, 256, 0, stream>>>(rowptr, epack, user_emb, item_emb, bufB, Oacc);
  k_spmm<<<37500, 256, 0, stream>>>(rowptr, epack, bufB, bufA, Oacc);
  k_spmm<<<37500, 256, 0, stream>>>(rowptr, epack, bufA, (float*)nullptr, Oacc);

  k_wt<<<16, 256, 0, stream>>>(uW1, WT);
  k_pw<<<1, 256, 0, stream>>>(pop_emb, gW1, iW1, hp, pp1);
  k_user<<<4, 64, 0, stream>>>(Oacc, users, user_bias, uW1T, ub1, uW2, ub2, Ut);
  k_gemm1z<<<391, 256, 0, stream>>>(Oacc, gW1, iW1, bins, hp, pp1, gb1, gW2, gb2, ib1, H1);
  k_gemm2<<<391, 256, 0, stream>>>(H1, iW2, ib2, I);
  k_scores<<<dim3(391, 2), 256, 0, stream>>>(I, Ut, item_bias, out);
}

// Round 3
// 590.194 us; speedup vs baseline: 1.1384x; 1.1384x over previous
//
#include <hip/hip_runtime.h>

#define N_USERS 100000
#define N_ITEMS 50000
#define N_NODES 150000
#define D 64
#define NNZ 2000000
#define BATCH 256
#define POP_BINS 10

// bucketed CSR params
#define BSH 9
#define NB2 293            // ceil(150000/512)
#define CAP 8192           // max edges per bucket (mean 6827, sigma ~82)
#define P1_EPB 4096        // edges per block in pass 1
#define P1_BLOCKS 489      // ceil(NNZ/P1_EPB)

#define ST_P 130           // I-tile LDS pad for transposed stages

// ---------------- bucket count: LDS histogram -> global ----------------------
__global__ __launch_bounds__(256) void k_bcount(const int* __restrict__ rows,
                                                int* __restrict__ bcnt) {
  __shared__ int c[NB2];
  int t = threadIdx.x;
  for (int i = t; i < NB2; i += 256) c[i] = 0;
  __syncthreads();
  int base = blockIdx.x * P1_EPB;
  for (int i = 0; i < 16; i++) {
    int e = base + i * 256 + t;
    if (e < NNZ) atomicAdd(&c[rows[e] >> BSH], 1);
  }
  __syncthreads();
  for (int i = t; i < NB2; i += 256)
    if (c[i]) atomicAdd(&bcnt[i], c[i]);
}

// ---------------- bucket scan: exclusive, in-place (becomes bcur) ------------
__global__ __launch_bounds__(512) void k_bscan(int* __restrict__ bcnt) {
  __shared__ int s[512];
  int t = threadIdx.x;
  int v = (t < NB2) ? bcnt[t] : 0;
  s[t] = v;
  __syncthreads();
  for (int o = 1; o < 512; o <<= 1) {
    int x = (t >= o) ? s[t - o] : 0;
    __syncthreads();
    s[t] += x;
    __syncthreads();
  }
  if (t < NB2) bcnt[t] = s[t] - v;  // exclusive base; p1 advances to inclusive
}

// ---------------- pass 1: bucket edges, TWO-PASS (no per-thread arrays) -----
__global__ __launch_bounds__(256) void k_p1(const int* __restrict__ rows,
                                            const int* __restrict__ cols,
                                            const float* __restrict__ vals,
                                            int* __restrict__ bcur,
                                            uint2* __restrict__ gstage) {
  __shared__ int cnt[NB2];
  __shared__ int gbase[NB2];
  int t = threadIdx.x;
  for (int i = t; i < NB2; i += 256) cnt[i] = 0;
  __syncthreads();
  int base = blockIdx.x * P1_EPB;
  // pass A: count buckets
  for (int i = 0; i < 16; i++) {
    int e = base + i * 256 + t;
    if (e < NNZ) atomicAdd(&cnt[rows[e] >> BSH], 1);
  }
  __syncthreads();
  for (int i = t; i < NB2; i += 256) {
    int c = cnt[i];
    gbase[i] = c ? atomicAdd(&bcur[i], c) : 0;
    cnt[i] = 0;
  }
  __syncthreads();
  // pass B: re-read (L2-hot) and scatter clustered
  for (int i = 0; i < 16; i++) {
    int e = base + i * 256 + t;
    if (e < NNZ) {
      int r = rows[e];
      int b = r >> BSH;
      int rank = atomicAdd(&cnt[b], 1);
      unsigned key = ((unsigned)(r & 511) << 18) | (unsigned)cols[e];
      gstage[gbase[b] + rank] = make_uint2(key, __float_as_uint(vals[e]));
    }
  }
}

// ---------------- pass 2: per-bucket LDS counting sort, contiguous writes ---
// Also produces rowptr (bucketbase + local exclusive scan).
__global__ __launch_bounds__(256) void k_p2(const int* __restrict__ bcur,
                                            const uint2* __restrict__ gstage,
                                            uint2* __restrict__ epack,
                                            int* __restrict__ rowptr) {
  __shared__ int cnt[512];
  __shared__ int off[512];
  __shared__ int s[256];
  __shared__ uint2 buf[CAP];
  int b = blockIdx.x, t = threadIdx.x;
  int base = (b == 0) ? 0 : bcur[b - 1];  // post-p1 bcur = inclusive scan
  int end = bcur[b];
  int n = end - base;
  cnt[t] = 0;
  cnt[t + 256] = 0;
  __syncthreads();
  for (int j = t; j < n; j += 256)
    atomicAdd(&cnt[gstage[base + j].x >> 18], 1);
  __syncthreads();
  // scan 512 entries (each thread owns 2)
  int c0 = cnt[2 * t], c1 = cnt[2 * t + 1];
  s[t] = c0 + c1;
  __syncthreads();
  for (int o = 1; o < 256; o <<= 1) {
    int x = (t >= o) ? s[t - o] : 0;
    __syncthreads();
    s[t] += x;
    __syncthreads();
  }
  int ex = t ? s[t - 1] : 0;
  off[2 * t] = ex;
  off[2 * t + 1] = ex + c0;
  int gr = (b << BSH) + 2 * t;
  if (gr < N_NODES) rowptr[gr] = base + ex;
  if (gr + 1 < N_NODES) rowptr[gr + 1] = base + ex + c0;
  if (b == NB2 - 1 && t == 0) rowptr[N_NODES] = NNZ;
  __syncthreads();
  for (int j = t; j < n; j += 256) {
    uint2 ed = gstage[base + j];
    int lr = ed.x >> 18;
    int pos = atomicAdd(&off[lr], 1);
    buf[pos] = make_uint2(ed.x & 0x3FFFFu, ed.y);
  }
  __syncthreads();
  for (int j = t; j < n; j += 256) epack[base + j] = buf[j];
}

// ---------------- batch-user flags + unique list ----------------------------
__global__ __launch_bounds__(256) void k_flags(const int* __restrict__ users,
                                               int* __restrict__ uflag,
                                               int* __restrict__ ulist,
                                               int* __restrict__ ucnt) {
  int u = users[threadIdx.x];
  if (atomicExch(&uflag[u], 1) == 0) {
    int p = atomicAdd(ucnt, 1);
    ulist[p] = u;
  }
}

// ---------------- SPMM layer 1: gather from emb directly, init Oacc ---------
// Oacc only for rows whose Oacc is ever read (items + batch users).
__global__ __launch_bounds__(256) void k_spmm1(const int* __restrict__ rowptr,
                                               const uint2* __restrict__ epack,
                                               const float* __restrict__ ue,
                                               const float* __restrict__ ie,
                                               const int* __restrict__ uflag,
                                               float* __restrict__ Eout,
                                               float* __restrict__ Oacc) {
  int wave = blockIdx.x * 4 + (threadIdx.x >> 6);
  int row = __builtin_amdgcn_readfirstlane(wave);
  if (row >= N_NODES) return;
  int lane = threadIdx.x & 63;
  int beg = rowptr[row];
  int end = rowptr[row + 1];
  float acc0 = 0.f, acc1 = 0.f;
  int j = beg;
  for (; j + 3 < end; j += 4) {
    uint2 e0 = epack[j], e1 = epack[j + 1], e2 = epack[j + 2], e3 = epack[j + 3];
    int c0 = (int)e0.x, c1 = (int)e1.x, c2 = (int)e2.x, c3 = (int)e3.x;
    const float* s0 = (c0 < N_USERS) ? ue + (size_t)c0 * D : ie + (size_t)(c0 - N_USERS) * D;
    const float* s1 = (c1 < N_USERS) ? ue + (size_t)c1 * D : ie + (size_t)(c1 - N_USERS) * D;
    const float* s2 = (c2 < N_USERS) ? ue + (size_t)c2 * D : ie + (size_t)(c2 - N_USERS) * D;
    const float* s3 = (c3 < N_USERS) ? ue + (size_t)c3 * D : ie + (size_t)(c3 - N_USERS) * D;
    acc0 += __uint_as_float(e0.y) * s0[lane];
    acc1 += __uint_as_float(e1.y) * s1[lane];
    acc0 += __uint_as_float(e2.y) * s2[lane];
    acc1 += __uint_as_float(e3.y) * s3[lane];
  }
  for (; j < end; ++j) {
    uint2 e0 = epack[j];
    int c0 = (int)e0.x;
    const float* s0 = (c0 < N_USERS) ? ue + (size_t)c0 * D : ie + (size_t)(c0 - N_USERS) * D;
    acc0 += __uint_as_float(e0.y) * s0[lane];
  }
  float acc = acc0 + acc1;
  int o = row * D + lane;
  Eout[o] = acc;
  bool need = (row >= N_USERS) || (uflag[row] != 0);
  if (need) {
    float e = (row < N_USERS) ? ue[(size_t)row * D + lane]
                              : ie[(size_t)(row - N_USERS) * D + lane];
    Oacc[o] = 0.25f * (e + acc);
  }
}

// ---------------- SPMM layer 2: full Eout, restricted Oacc ------------------
__global__ __launch_bounds__(256) void k_spmm(const int* __restrict__ rowptr,
                                              const uint2* __restrict__ epack,
                                              const float* __restrict__ Ein,
                                              const int* __restrict__ uflag,
                                              float* __restrict__ Eout,
                                              float* __restrict__ Oacc) {
  int wave = blockIdx.x * 4 + (threadIdx.x >> 6);
  int row = __builtin_amdgcn_readfirstlane(wave);
  if (row >= N_NODES) return;
  int lane = threadIdx.x & 63;
  int beg = rowptr[row];
  int end = rowptr[row + 1];
  float acc0 = 0.f, acc1 = 0.f;
  int j = beg;
  for (; j + 3 < end; j += 4) {
    uint2 e0 = epack[j], e1 = epack[j + 1], e2 = epack[j + 2], e3 = epack[j + 3];
    acc0 += __uint_as_float(e0.y) * Ein[(size_t)e0.x * D + lane];
    acc1 += __uint_as_float(e1.y) * Ein[(size_t)e1.x * D + lane];
    acc0 += __uint_as_float(e2.y) * Ein[(size_t)e2.x * D + lane];
    acc1 += __uint_as_float(e3.y) * Ein[(size_t)e3.x * D + lane];
  }
  for (; j < end; ++j) {
    uint2 e0 = epack[j];
    acc0 += __uint_as_float(e0.y) * Ein[(size_t)e0.x * D + lane];
  }
  float acc = acc0 + acc1;
  int o = row * D + lane;
  Eout[o] = acc;
  if (row >= N_USERS || uflag[row] != 0) Oacc[o] += 0.25f * acc;
}

// ---------------- SPMM layer 3: ONLY needed rows (items + batch users) ------
// Items are rows [N_USERS, N_NODES): contiguous epack region, streams nicely.
// Batch users come from the deduped ulist (ucnt <= 256).
__global__ __launch_bounds__(256) void k_spmm3(const int* __restrict__ rowptr,
                                               const uint2* __restrict__ epack,
                                               const float* __restrict__ Ein,
                                               const int* __restrict__ ulist,
                                               const int* __restrict__ ucnt,
                                               float* __restrict__ Oacc) {
  int w = blockIdx.x * 4 + (threadIdx.x >> 6);
  int row;
  if (w < N_ITEMS) {
    row = N_USERS + w;
  } else {
    int k = w - N_ITEMS;
    if (k >= ucnt[0]) return;
    row = ulist[k];
  }
  row = __builtin_amdgcn_readfirstlane(row);
  int lane = threadIdx.x & 63;
  int beg = rowptr[row];
  int end = rowptr[row + 1];
  float acc0 = 0.f, acc1 = 0.f;
  int j = beg;
  for (; j + 3 < end; j += 4) {
    uint2 e0 = epack[j], e1 = epack[j + 1], e2 = epack[j + 2], e3 = epack[j + 3];
    acc0 += __uint_as_float(e0.y) * Ein[(size_t)e0.x * D + lane];
    acc1 += __uint_as_float(e1.y) * Ein[(size_t)e1.x * D + lane];
    acc0 += __uint_as_float(e2.y) * Ein[(size_t)e2.x * D + lane];
    acc1 += __uint_as_float(e3.y) * Ein[(size_t)e3.x * D + lane];
  }
  for (; j < end; ++j) {
    uint2 e0 = epack[j];
    acc0 += __uint_as_float(e0.y) * Ein[(size_t)e0.x * D + lane];
  }
  int o = row * D + lane;
  Oacc[o] += 0.25f * (acc0 + acc1);
}

// ---------------- weight transpose: uW1T[64][64] (for k_user) ---------------
__global__ __launch_bounds__(256) void k_wt(const float* __restrict__ uW1,
                                            float* __restrict__ WT) {
  int t = blockIdx.x * 256 + threadIdx.x;
  if (t < 4096) {
    int o = t >> 6, k = t & 63;
    WT[t] = uW1[k * 64 + o];
  }
}

// ---------------- pop-row precompute: hp[b]=p_b@gW1_p, pp1[b]=p_b@iW1 -------
__global__ __launch_bounds__(256) void k_pw(const float* __restrict__ pop,
                                            const float* __restrict__ gW1,
                                            const float* __restrict__ iW1,
                                            float* __restrict__ hp,
                                            float* __restrict__ pp1) {
  for (int idx = threadIdx.x; idx < 2 * POP_BINS * 64; idx += 256) {
    int q = idx;
    bool second = q >= POP_BINS * 64;
    if (second) q -= POP_BINS * 64;
    int b = q >> 6, o = q & 63;
    float s = 0.f;
    if (!second) {
      for (int k = 0; k < 64; k++) s += pop[b * 64 + k] * gW1[(64 + k) * 64 + o];
      hp[q] = s;
    } else {
      for (int k = 0; k < 64; k++) s += pop[b * 64 + k] * iW1[k * 64 + o];
      pp1[q] = s;
    }
  }
}

// ---------------- user MLP: thread per user, all state in VGPRs -------------
// NOTE: every acc[] access is compile-time-indexed (full unroll) so the
// array register-allocates; a "#pragma unroll 1" store loop would force
// acc[64] into scratch (rule #20).
__global__ __launch_bounds__(64) void k_user(const float* __restrict__ Oacc,
                                             const int* __restrict__ users,
                                             const float* __restrict__ ubias,
                                             const float* __restrict__ uW1T,
                                             const float* __restrict__ ub1,
                                             const float* __restrict__ uW2,
                                             const float* __restrict__ ub2,
                                             float* __restrict__ Ut) {
  int b = blockIdx.x * 64 + threadIdx.x;
  int u = users[b];
  float x[64];
  const float4* xr = (const float4*)(Oacc + (size_t)u * 64);
#pragma unroll
  for (int q = 0; q < 16; q++) {
    float4 t4 = xr[q];
    x[4 * q] = t4.x; x[4 * q + 1] = t4.y; x[4 * q + 2] = t4.z; x[4 * q + 3] = t4.w;
  }
  float acc[64];
#pragma unroll
  for (int o2 = 0; o2 < 64; o2++) acc[o2] = ub2[o2];
#pragma unroll 1
  for (int o = 0; o < 64; o++) {
    const float* w = uW1T + o * 64;
    float a0 = ub1[o], a1 = 0.f, a2 = 0.f, a3 = 0.f;
#pragma unroll
    for (int k = 0; k < 64; k += 4) {
      a0 += x[k] * w[k]; a1 += x[k + 1] * w[k + 1];
      a2 += x[k + 2] * w[k + 2]; a3 += x[k + 3] * w[k + 3];
    }
    float hv = a0 + a1 + a2 + a3;
    hv = hv > 0.f ? hv : 0.f;
    const float* w2 = uW2 + o * 64;
#pragma unroll
    for (int o2 = 0; o2 < 64; o2++) acc[o2] += hv * w2[o2];
  }
#pragma unroll
  for (int o2 = 0; o2 < 64; o2++) Ut[o2 * 256 + b] = acc[o2];
  Ut[64 * 256 + b] = ubias[u];  // BIAS_SCALE = 1.0
}

// ---------------- GEMM1 fused with gate (G|T in regs -> z -> H1) ------------
__global__ __launch_bounds__(256) void k_gemm1z(const float* __restrict__ Oacc,
                                                const float* __restrict__ gW1,
                                                const float* __restrict__ iW1,
                                                const int* __restrict__ bins,
                                                const float* __restrict__ hp,
                                                const float* __restrict__ pp1,
                                                const float* __restrict__ gb1,
                                                const float* __restrict__ gW2,
                                                const float* __restrict__ gb2,
                                                const float* __restrict__ ib1,
                                                float* __restrict__ H1) {
  __shared__ float Is[64 * ST_P];
  __shared__ float Bs[64 * 128];
  __shared__ float zp[128][9];   // z partials, padded
  __shared__ float zs[128];      // final z per item
  int tid = threadIdx.x;
  int i0 = blockIdx.x * 128;
  {
    int c4 = tid & 15, r0 = tid >> 4;
#pragma unroll
    for (int s = 0; s < 8; s++) {
      int r = r0 + s * 16;
      int it = i0 + r;
      float4 v = make_float4(0.f, 0.f, 0.f, 0.f);
      if (it < N_ITEMS) v = *(const float4*)(Oacc + (size_t)(N_USERS + it) * 64 + c4 * 4);
      Is[(c4 * 4 + 0) * ST_P + r] = v.x;
      Is[(c4 * 4 + 1) * ST_P + r] = v.y;
      Is[(c4 * 4 + 2) * ST_P + r] = v.z;
      Is[(c4 * 4 + 3) * ST_P + r] = v.w;
    }
  }
  for (int idx = tid; idx < 64 * 128; idx += 256) {
    int k = idx >> 7, o = idx & 127;
    Bs[idx] = (o < 64) ? gW1[k * 64 + o] : iW1[k * 64 + (o - 64)];
  }
  __syncthreads();
  int tx = tid & 15, ty = tid >> 4;
  float acc[8][8];
#pragma unroll
  for (int a = 0; a < 8; a++)
#pragma unroll
    for (int b = 0; b < 8; b++) acc[a][b] = 0.f;
  const float* ip = Is + tx * 8;
  const float* wp = Bs + ty * 8;
#pragma unroll 2
  for (int k = 0; k < 64; k++) {
    float4 iv0 = *(const float4*)(ip + k * ST_P);
    float4 iv1 = *(const float4*)(ip + k * ST_P + 4);
    float4 wv0 = *(const float4*)(wp + k * 128);
    float4 wv1 = *(const float4*)(wp + k * 128 + 4);
    float iv[8] = {iv0.x, iv0.y, iv0.z, iv0.w, iv1.x, iv1.y, iv1.z, iv1.w};
    float wv[8] = {wv0.x, wv0.y, wv0.z, wv0.w, wv1.x, wv1.y, wv1.z, wv1.w};
#pragma unroll
    for (int a = 0; a < 8; a++)
#pragma unroll
      for (int b = 0; b < 8; b++) acc[a][b] += iv[a] * wv[b];
  }
  int ibase = i0 + tx * 8;
  // --- gate epilogue ---
  if (ty < 8) {  // G half: z partials over this thread's 8 o-columns
    int o0 = ty * 8;
#pragma unroll
    for (int a = 0; a < 8; a++) {
      int it = ibase + a;
      float p = 0.f;
      if (it < N_ITEMS) {
        int bin = bins[it];
        const float* hpr = hp + bin * 64 + o0;
#pragma unroll
        for (int b = 0; b < 8; b++) {
          float g = acc[a][b] + hpr[b] + gb1[o0 + b];
          g = g > 0.f ? g : 0.f;
          p += g * gW2[o0 + b];
        }
      }
      zp[tx * 8 + a][ty] = p;
    }
  }
  __syncthreads();
  if (tid < 128) {
    float s = gb2[0];
#pragma unroll
    for (int k = 0; k < 8; k++) s += zp[tid][k];
    zs[tid] = 1.f / (1.f + expf(-s));
  }
  __syncthreads();
  if (ty >= 8) {  // T half: fuse + relu -> H1
    int o0 = (ty - 8) * 8;
#pragma unroll
    for (int a = 0; a < 8; a++) {
      int it = ibase + a;
      if (it < N_ITEMS) {
        float z = zs[tx * 8 + a];
        int bin = bins[it];
        const float* ppr = pp1 + bin * 64 + o0;
        float h[8];
#pragma unroll
        for (int b = 0; b < 8; b++) {
          float v = (1.f - z) * acc[a][b] + z * ppr[b] + ib1[o0 + b];
          h[b] = v > 0.f ? v : 0.f;
        }
        *(float4*)(H1 + (size_t)it * 64 + o0) = make_float4(h[0], h[1], h[2], h[3]);
        *(float4*)(H1 + (size_t)it * 64 + o0 + 4) = make_float4(h[4], h[5], h[6], h[7]);
      }
    }
  }
}

// ---------------- GEMM2: I = H1 @ iW2 + ib2  (128x64 tile, K=64) ------------
__global__ __launch_bounds__(256) void k_gemm2(const float* __restrict__ H1,
                                               const float* __restrict__ iW2,
                                               const float* __restrict__ ib2,
                                               float* __restrict__ I) {
  __shared__ float Is[64 * ST_P];
  __shared__ float Bs[64 * 64];
  int tid = threadIdx.x;
  int i0 = blockIdx.x * 128;
  {
    int c4 = tid & 15, r0 = tid >> 4;
#pragma unroll
    for (int s = 0; s < 8; s++) {
      int r = r0 + s * 16;
      int it = i0 + r;
      float4 v = make_float4(0.f, 0.f, 0.f, 0.f);
      if (it < N_ITEMS) v = *(const float4*)(H1 + (size_t)it * 64 + c4 * 4);
      Is[(c4 * 4 + 0) * ST_P + r] = v.x;
      Is[(c4 * 4 + 1) * ST_P + r] = v.y;
      Is[(c4 * 4 + 2) * ST_P + r] = v.z;
      Is[(c4 * 4 + 3) * ST_P + r] = v.w;
    }
  }
  for (int idx = tid; idx < 64 * 64; idx += 256) Bs[idx] = iW2[idx];
  __syncthreads();
  int tx = tid & 15, ty = tid >> 4;
  float acc[8][4];
#pragma unroll
  for (int a = 0; a < 8; a++)
#pragma unroll
    for (int b = 0; b < 4; b++) acc[a][b] = 0.f;
  const float* ip = Is + tx * 8;
  const float* wp = Bs + ty * 4;
#pragma unroll 2
  for (int k = 0; k < 64; k++) {
    float4 iv0 = *(const float4*)(ip + k * ST_P);
    float4 iv1 = *(const float4*)(ip + k * ST_P + 4);
    float4 wv = *(const float4*)(wp + k * 64);
    float iv[8] = {iv0.x, iv0.y, iv0.z, iv0.w, iv1.x, iv1.y, iv1.z, iv1.w};
    float wvv[4] = {wv.x, wv.y, wv.z, wv.w};
#pragma unroll
    for (int a = 0; a < 8; a++)
#pragma unroll
      for (int b = 0; b < 4; b++) acc[a][b] += iv[a] * wvv[b];
  }
  int ibase = i0 + tx * 8;
  int oc = ty * 4;
  float b0 = ib2[oc], b1 = ib2[oc + 1], b2 = ib2[oc + 2], b3 = ib2[oc + 3];
#pragma unroll
  for (int a = 0; a < 8; a++) {
    int it = ibase + a;
    if (it < N_ITEMS) {
      float4 s0 = make_float4(acc[a][0] + b0, acc[a][1] + b1,
                              acc[a][2] + b2, acc[a][3] + b3);
      *(float4*)(I + (size_t)it * 64 + oc) = s0;
    }
  }
}

// ---------------- scores: 128x128 tile GEMM, 8x8 register blocking ----------
__global__ __launch_bounds__(256) void k_scores(const float* __restrict__ I,
                                                const float* __restrict__ Ut,
                                                const float* __restrict__ item_bias,
                                                float* __restrict__ out) {
  __shared__ float Is[64 * ST_P];
  __shared__ float Us[64 * 128];
  int tid = threadIdx.x;
  int i0 = blockIdx.x * 128;
  int ubase = blockIdx.y * 128;
  {
    int c4 = tid & 15, r0 = tid >> 4;
#pragma unroll
    for (int s = 0; s < 8; s++) {
      int r = r0 + s * 16;
      int it = i0 + r;
      float4 v = make_float4(0.f, 0.f, 0.f, 0.f);
      if (it < N_ITEMS) v = *(const float4*)(I + (size_t)it * 64 + c4 * 4);
      Is[(c4 * 4 + 0) * ST_P + r] = v.x;
      Is[(c4 * 4 + 1) * ST_P + r] = v.y;
      Is[(c4 * 4 + 2) * ST_P + r] = v.z;
      Is[(c4 * 4 + 3) * ST_P + r] = v.w;
    }
  }
  {
    int u4 = tid & 31, k0 = tid >> 5;
#pragma unroll
    for (int s = 0; s < 8; s++) {
      int k = k0 + s * 8;
      float4 v = *(const float4*)(Ut + k * 256 + ubase + u4 * 4);
      *(float4*)(Us + k * 128 + u4 * 4) = v;
    }
  }
  __syncthreads();
  int tx = tid & 15;
  int ty = tid >> 4;
  float acc[8][8];
#pragma unroll
  for (int a = 0; a < 8; a++)
#pragma unroll
    for (int b = 0; b < 8; b++) acc[a][b] = 0.f;
  const float* ip = Is + tx * 8;
  const float* up = Us + ty * 8;
#pragma unroll 2
  for (int k = 0; k < 64; k++) {
    float4 iv0 = *(const float4*)(ip + k * ST_P);
    float4 iv1 = *(const float4*)(ip + k * ST_P + 4);
    float4 uv0 = *(const float4*)(up + k * 128);
    float4 uv1 = *(const float4*)(up + k * 128 + 4);
    float iv[8] = {iv0.x, iv0.y, iv0.z, iv0.w, iv1.x, iv1.y, iv1.z, iv1.w};
    float uv[8] = {uv0.x, uv0.y, uv0.z, uv0.w, uv1.x, uv1.y, uv1.z, uv1.w};
#pragma unroll
    for (int a = 0; a < 8; a++)
#pragma unroll
      for (int b = 0; b < 8; b++) acc[a][b] += iv[a] * uv[b];
  }
  int ibase = i0 + tx * 8;
  float ib[8];
#pragma unroll
  for (int a = 0; a < 8; a++)
    ib[a] = (ibase + a < N_ITEMS) ? item_bias[ibase + a] : 0.f;
#pragma unroll
  for (int bb = 0; bb < 8; bb++) {
    int bu = ubase + ty * 8 + bb;
    float ubias = Ut[64 * 256 + bu];
    float* orow = out + (size_t)bu * N_ITEMS + ibase;
    if (ibase + 7 < N_ITEMS) {
      float4 s0 = make_float4(acc[0][bb] + ubias + ib[0], acc[1][bb] + ubias + ib[1],
                              acc[2][bb] + ubias + ib[2], acc[3][bb] + ubias + ib[3]);
      float4 s1 = make_float4(acc[4][bb] + ubias + ib[4], acc[5][bb] + ubias + ib[5],
                              acc[6][bb] + ubias + ib[6], acc[7][bb] + ubias + ib[7]);
      *(float4*)orow = s0;
      *(float4*)(orow + 4) = s1;
    } else {
#pragma unroll
      for (int a = 0; a < 8; a++)
        if (ibase + a < N_ITEMS) orow[a] = acc[a][bb] + ubias + ib[a];
    }
  }
}

extern "C" void kernel_launch(void* const* d_in, const int* in_sizes, int n_in,
                              void* d_out, int out_size, void* d_ws, size_t ws_size,
                              hipStream_t stream) {
  const float* user_emb  = (const float*)d_in[0];
  const float* item_emb  = (const float*)d_in[1];
  const float* user_bias = (const float*)d_in[2];
  const float* item_bias = (const float*)d_in[3];
  const float* pop_emb   = (const float*)d_in[4];
  const float* uW1 = (const float*)d_in[5];
  const float* ub1 = (const float*)d_in[6];
  const float* uW2 = (const float*)d_in[7];
  const float* ub2 = (const float*)d_in[8];
  const float* iW1 = (const float*)d_in[9];
  const float* ib1 = (const float*)d_in[10];
  const float* iW2 = (const float*)d_in[11];
  const float* ib2 = (const float*)d_in[12];
  const float* gW1 = (const float*)d_in[13];
  const float* gb1 = (const float*)d_in[14];
  const float* gW2 = (const float*)d_in[15];
  const float* gb2 = (const float*)d_in[16];
  const float* adj_vals = (const float*)d_in[17];
  const int* adj_rows = (const int*)d_in[18];
  const int* adj_cols = (const int*)d_in[19];
  const int* bins  = (const int*)d_in[20];
  const int* users = (const int*)d_in[21];
  float* out = (float*)d_out;

  // workspace layout (float offsets); total ~132.7 MB
  // rowptr spans [32800000, 32950001) in int units -> uflag placed AFTER it.
  float* ws = (float*)d_ws;
  float* Oacc = ws;                    // 9,600,000
  float* bufA = ws + 9600000;          // 9,600,000 (E2; H1 in top third after)
  float* bufB = ws + 19200000;         // 9,600,000 (gstage pre-spmm; E1; I after)
  uint2* epack = (uint2*)(ws + 28800000);      // 2,000,000 * 8B -> ends 32800000
  int* rowptr = (int*)(ws + 32800000);         // 150,001 ints -> ends 32950001
  int* uflag  = (int*)(ws + 32960000);         // 100,000 ints -> ends 33060000
  int* ucnt   = (int*)(ws + 33060000);         // 1 (uflag+100000: one memset)
  int* ulist  = (int*)(ws + 33061000);         // 256
  float* Ut   = ws + 33130000;                 // 65*256 -> ends 33146640
  float* WT   = ws + 33150000;                 // 4,096 (uW1T)
  float* hp   = ws + 33160000;                 // 640
  float* pp1  = ws + 33161000;                 // 640
  int* bcur   = (int*)(ws + 33170000);         // 293 (bcnt -> excl scan -> cursor)
  uint2* gstage = (uint2*)bufB;
  float* E1 = bufB;                            // full 9,600,000
  float* E2 = bufA;                            // full 9,600,000
  float* H1 = bufA + 6400000;                  // 3,200,000 (E2 dead by then)
  float* I  = bufB;                            // 3,200,000
  const float* uW1T = WT;

  hipMemsetAsync(bcur, 0, NB2 * sizeof(int), stream);
  hipMemsetAsync(uflag, 0, 100001 * sizeof(int), stream);  // covers uflag+ucnt
  k_bcount<<<P1_BLOCKS, 256, 0, stream>>>(adj_rows, bcur);
  k_bscan<<<1, 512, 0, stream>>>(bcur);
  k_p1<<<P1_BLOCKS, 256, 0, stream>>>(adj_rows, adj_cols, adj_vals, bcur, gstage);
  k_p2<<<NB2, 256, 0, stream>>>(bcur, gstage, epack, rowptr);
  k_flags<<<1, 256, 0, stream>>>(users, uflag, ulist, ucnt);

  k_spmm1<<<37500, 256, 0, stream>>>(rowptr, epack, user_emb, item_emb, uflag, E1, Oacc);
  k_spmm<<<37500, 256, 0, stream>>>(rowptr, epack, E1, uflag, E2, Oacc);
  k_spmm3<<<12564, 256, 0, stream>>>(rowptr, epack, E2, ulist, ucnt, Oacc);

  k_wt<<<16, 256, 0, stream>>>(uW1, WT);
  k_pw<<<1, 256, 0, stream>>>(pop_emb, gW1, iW1, hp, pp1);
  k_user<<<4, 64, 0, stream>>>(Oacc, users, user_bias, uW1T, ub1, uW2, ub2, Ut);
  k_gemm1z<<<391, 256, 0, stream>>>(Oacc, gW1, iW1, bins, hp, pp1, gb1, gW2, gb2, ib1, H1);
  k_gemm2<<<391, 256, 0, stream>>>(H1, iW2, ib2, I);
  k_scores<<<dim3(391, 2), 256, 0, stream>>>(I, Ut, item_bias, out);
}

// Round 4
// 563.317 us; speedup vs baseline: 1.1927x; 1.0477x over previous
//
#include <hip/hip_runtime.h>
#include <hip/hip_fp16.h>

#define N_USERS 100000
#define N_ITEMS 50000
#define N_NODES 150000
#define D 64
#define NNZ 2000000
#define BATCH 256
#define POP_BINS 10

// bucketed CSR params
#define BSH 9
#define NB2 293            // ceil(150000/512)
#define CAP 8192           // max edges per bucket (mean 6827, sigma ~82)
#define P1_EPB 4096        // edges per block in pass 1
#define P1_BLOCKS 489      // ceil(NNZ/P1_EPB)

#define ST_P 130           // I-tile LDS pad for transposed stages

// ---------------- bucket count: LDS histogram -> global ----------------------
__global__ __launch_bounds__(256) void k_bcount(const int* __restrict__ rows,
                                                int* __restrict__ bcnt) {
  __shared__ int c[NB2];
  int t = threadIdx.x;
  for (int i = t; i < NB2; i += 256) c[i] = 0;
  __syncthreads();
  int base = blockIdx.x * P1_EPB;
  for (int i = 0; i < 16; i++) {
    int e = base + i * 256 + t;
    if (e < NNZ) atomicAdd(&c[rows[e] >> BSH], 1);
  }
  __syncthreads();
  for (int i = t; i < NB2; i += 256)
    if (c[i]) atomicAdd(&bcnt[i], c[i]);
}

// ---------------- bucket scan: exclusive, in-place (becomes bcur) ------------
__global__ __launch_bounds__(512) void k_bscan(int* __restrict__ bcnt) {
  __shared__ int s[512];
  int t = threadIdx.x;
  int v = (t < NB2) ? bcnt[t] : 0;
  s[t] = v;
  __syncthreads();
  for (int o = 1; o < 512; o <<= 1) {
    int x = (t >= o) ? s[t - o] : 0;
    __syncthreads();
    s[t] += x;
    __syncthreads();
  }
  if (t < NB2) bcnt[t] = s[t] - v;  // exclusive base; p1 advances to inclusive
}

// ---------------- pass 1: bucket edges, TWO-PASS (no per-thread arrays) -----
__global__ __launch_bounds__(256) void k_p1(const int* __restrict__ rows,
                                            const int* __restrict__ cols,
                                            const float* __restrict__ vals,
                                            int* __restrict__ bcur,
                                            uint2* __restrict__ gstage) {
  __shared__ int cnt[NB2];
  __shared__ int gbase[NB2];
  int t = threadIdx.x;
  for (int i = t; i < NB2; i += 256) cnt[i] = 0;
  __syncthreads();
  int base = blockIdx.x * P1_EPB;
  // pass A: count buckets
  for (int i = 0; i < 16; i++) {
    int e = base + i * 256 + t;
    if (e < NNZ) atomicAdd(&cnt[rows[e] >> BSH], 1);
  }
  __syncthreads();
  for (int i = t; i < NB2; i += 256) {
    int c = cnt[i];
    gbase[i] = c ? atomicAdd(&bcur[i], c) : 0;
    cnt[i] = 0;
  }
  __syncthreads();
  // pass B: re-read (L2-hot) and scatter clustered
  for (int i = 0; i < 16; i++) {
    int e = base + i * 256 + t;
    if (e < NNZ) {
      int r = rows[e];
      int b = r >> BSH;
      int rank = atomicAdd(&cnt[b], 1);
      unsigned key = ((unsigned)(r & 511) << 18) | (unsigned)cols[e];
      gstage[gbase[b] + rank] = make_uint2(key, __float_as_uint(vals[e]));
    }
  }
}

// ---------------- pass 2: per-bucket LDS counting sort, contiguous writes ---
// Also produces rowptr (bucketbase + local exclusive scan).
__global__ __launch_bounds__(256) void k_p2(const int* __restrict__ bcur,
                                            const uint2* __restrict__ gstage,
                                            uint2* __restrict__ epack,
                                            int* __restrict__ rowptr) {
  __shared__ int cnt[512];
  __shared__ int off[512];
  __shared__ int s[256];
  __shared__ uint2 buf[CAP];
  int b = blockIdx.x, t = threadIdx.x;
  int base = (b == 0) ? 0 : bcur[b - 1];  // post-p1 bcur = inclusive scan
  int end = bcur[b];
  int n = end - base;
  cnt[t] = 0;
  cnt[t + 256] = 0;
  __syncthreads();
  for (int j = t; j < n; j += 256)
    atomicAdd(&cnt[gstage[base + j].x >> 18], 1);
  __syncthreads();
  // scan 512 entries (each thread owns 2)
  int c0 = cnt[2 * t], c1 = cnt[2 * t + 1];
  s[t] = c0 + c1;
  __syncthreads();
  for (int o = 1; o < 256; o <<= 1) {
    int x = (t >= o) ? s[t - o] : 0;
    __syncthreads();
    s[t] += x;
    __syncthreads();
  }
  int ex = t ? s[t - 1] : 0;
  off[2 * t] = ex;
  off[2 * t + 1] = ex + c0;
  int gr = (b << BSH) + 2 * t;
  if (gr < N_NODES) rowptr[gr] = base + ex;
  if (gr + 1 < N_NODES) rowptr[gr + 1] = base + ex + c0;
  if (b == NB2 - 1 && t == 0) rowptr[N_NODES] = NNZ;
  __syncthreads();
  for (int j = t; j < n; j += 256) {
    uint2 ed = gstage[base + j];
    int lr = ed.x >> 18;
    int pos = atomicAdd(&off[lr], 1);
    buf[pos] = make_uint2(ed.x & 0x3FFFFu, ed.y);
  }
  __syncthreads();
  for (int j = t; j < n; j += 256) epack[base + j] = buf[j];
}

// ---------------- batch-user flags + unique list ----------------------------
__global__ __launch_bounds__(256) void k_flags(const int* __restrict__ users,
                                               int* __restrict__ uflag,
                                               int* __restrict__ ulist,
                                               int* __restrict__ ucnt) {
  int u = users[threadIdx.x];
  if (atomicExch(&uflag[u], 1) == 0) {
    int p = atomicAdd(ucnt, 1);
    ulist[p] = u;
  }
}

// ---------------- emb -> fp16 combined table --------------------------------
// Eh0[n][d] = (n < N_USERS ? ue : ie)[...] as fp16. 2.4M float4s.
__global__ __launch_bounds__(256) void k_cvt(const float* __restrict__ ue,
                                             const float* __restrict__ ie,
                                             __half* __restrict__ Eh) {
  int t = blockIdx.x * 256 + threadIdx.x;     // float4 index, < 2,400,000
  if (t >= 2400000) return;
  size_t fo = (size_t)t * 4;
  const float* src = (fo < (size_t)N_USERS * 64) ? ue + fo
                                                 : ie + (fo - (size_t)N_USERS * 64);
  float4 v = *(const float4*)src;
  __half2* dst = (__half2*)(Eh + fo);
  dst[0] = __floats2half2_rn(v.x, v.y);
  dst[1] = __floats2half2_rn(v.z, v.w);
}

// ---------------- SPMM layer 1: fp16 gather, 2 edges per wave-request -------
// lane = 32*h + p: half-wave h handles edge j+h; lane covers cols {2p,2p+1}.
// One __half2 load per lane serves 2 edges (4 cache lines / 2 edges vs 4/1).
__global__ __launch_bounds__(256) void k_spmm1(const int* __restrict__ rowptr,
                                               const uint2* __restrict__ epack,
                                               const float* __restrict__ ue,
                                               const float* __restrict__ ie,
                                               const __half* __restrict__ Eh0,
                                               const int* __restrict__ uflag,
                                               __half* __restrict__ EoutH,
                                               float* __restrict__ Oacc) {
  int wave = blockIdx.x * 4 + (threadIdx.x >> 6);
  int row = __builtin_amdgcn_readfirstlane(wave);
  if (row >= N_NODES) return;
  int lane = threadIdx.x & 63;
  int p = lane & 31, h = lane >> 5;
  int beg = rowptr[row];
  int end = rowptr[row + 1];
  float ax = 0.f, ay = 0.f, bx = 0.f, by = 0.f;
  int j = beg;
  for (; j + 3 < end; j += 4) {
    uint2 e0 = epack[j], e1 = epack[j + 1], e2 = epack[j + 2], e3 = epack[j + 3];
    uint2 ea = h ? e1 : e0;
    uint2 eb = h ? e3 : e2;
    __half2 ga = *(const __half2*)(Eh0 + (size_t)ea.x * 64 + 2 * p);
    __half2 gb = *(const __half2*)(Eh0 + (size_t)eb.x * 64 + 2 * p);
    float va = __uint_as_float(ea.y), vb = __uint_as_float(eb.y);
    float2 gaf = __half22float2(ga), gbf = __half22float2(gb);
    ax += va * gaf.x; ay += va * gaf.y;
    bx += vb * gbf.x; by += vb * gbf.y;
  }
  if (j + 1 < end) {
    uint2 e0 = epack[j], e1 = epack[j + 1];
    uint2 ea = h ? e1 : e0;
    __half2 ga = *(const __half2*)(Eh0 + (size_t)ea.x * 64 + 2 * p);
    float va = __uint_as_float(ea.y);
    float2 gaf = __half22float2(ga);
    ax += va * gaf.x; ay += va * gaf.y;
    j += 2;
  }
  if (j < end && h == 0) {
    uint2 e0 = epack[j];
    __half2 ga = *(const __half2*)(Eh0 + (size_t)e0.x * 64 + 2 * p);
    float va = __uint_as_float(e0.y);
    float2 gaf = __half22float2(ga);
    ax += va * gaf.x; ay += va * gaf.y;
  }
  float ox = ax + bx, oy = ay + by;
  ox += __shfl_xor(ox, 32, 64);
  oy += __shfl_xor(oy, 32, 64);
  if (h == 0) {
    *(__half2*)(EoutH + (size_t)row * 64 + 2 * p) = __floats2half2_rn(ox, oy);
    bool need = (row >= N_USERS) || (uflag[row] != 0);
    if (need) {
      const float* srow = (row < N_USERS) ? ue + (size_t)row * 64
                                          : ie + (size_t)(row - N_USERS) * 64;
      float2 sv = *(const float2*)(srow + 2 * p);
      *(float2*)(Oacc + (size_t)row * 64 + 2 * p) =
          make_float2(0.25f * (sv.x + ox), 0.25f * (sv.y + oy));
    }
  }
}

// ---------------- SPMM layer 2: fp16 in/out, restricted Oacc += -------------
__global__ __launch_bounds__(256) void k_spmm2h(const int* __restrict__ rowptr,
                                                const uint2* __restrict__ epack,
                                                const __half* __restrict__ Ein,
                                                const int* __restrict__ uflag,
                                                __half* __restrict__ EoutH,
                                                float* __restrict__ Oacc) {
  int wave = blockIdx.x * 4 + (threadIdx.x >> 6);
  int row = __builtin_amdgcn_readfirstlane(wave);
  if (row >= N_NODES) return;
  int lane = threadIdx.x & 63;
  int p = lane & 31, h = lane >> 5;
  int beg = rowptr[row];
  int end = rowptr[row + 1];
  float ax = 0.f, ay = 0.f, bx = 0.f, by = 0.f;
  int j = beg;
  for (; j + 3 < end; j += 4) {
    uint2 e0 = epack[j], e1 = epack[j + 1], e2 = epack[j + 2], e3 = epack[j + 3];
    uint2 ea = h ? e1 : e0;
    uint2 eb = h ? e3 : e2;
    __half2 ga = *(const __half2*)(Ein + (size_t)ea.x * 64 + 2 * p);
    __half2 gb = *(const __half2*)(Ein + (size_t)eb.x * 64 + 2 * p);
    float va = __uint_as_float(ea.y), vb = __uint_as_float(eb.y);
    float2 gaf = __half22float2(ga), gbf = __half22float2(gb);
    ax += va * gaf.x; ay += va * gaf.y;
    bx += vb * gbf.x; by += vb * gbf.y;
  }
  if (j + 1 < end) {
    uint2 e0 = epack[j], e1 = epack[j + 1];
    uint2 ea = h ? e1 : e0;
    __half2 ga = *(const __half2*)(Ein + (size_t)ea.x * 64 + 2 * p);
    float va = __uint_as_float(ea.y);
    float2 gaf = __half22float2(ga);
    ax += va * gaf.x; ay += va * gaf.y;
    j += 2;
  }
  if (j < end && h == 0) {
    uint2 e0 = epack[j];
    __half2 ga = *(const __half2*)(Ein + (size_t)e0.x * 64 + 2 * p);
    float va = __uint_as_float(e0.y);
    float2 gaf = __half22float2(ga);
    ax += va * gaf.x; ay += va * gaf.y;
  }
  float ox = ax + bx, oy = ay + by;
  ox += __shfl_xor(ox, 32, 64);
  oy += __shfl_xor(oy, 32, 64);
  if (h == 0) {
    *(__half2*)(EoutH + (size_t)row * 64 + 2 * p) = __floats2half2_rn(ox, oy);
    if (row >= N_USERS || uflag[row] != 0) {
      float2* op = (float2*)(Oacc + (size_t)row * 64 + 2 * p);
      float2 cur = *op;
      *op = make_float2(cur.x + 0.25f * ox, cur.y + 0.25f * oy);
    }
  }
}

// ---------------- SPMM layer 3: only needed rows, fp16 gather, Oacc += ------
__global__ __launch_bounds__(256) void k_spmm3h(const int* __restrict__ rowptr,
                                                const uint2* __restrict__ epack,
                                                const __half* __restrict__ Ein,
                                                const int* __restrict__ ulist,
                                                const int* __restrict__ ucnt,
                                                float* __restrict__ Oacc) {
  int w = blockIdx.x * 4 + (threadIdx.x >> 6);
  int row;
  if (w < N_ITEMS) {
    row = N_USERS + w;
  } else {
    int k = w - N_ITEMS;
    if (k >= ucnt[0]) return;
    row = ulist[k];
  }
  row = __builtin_amdgcn_readfirstlane(row);
  int lane = threadIdx.x & 63;
  int p = lane & 31, h = lane >> 5;
  int beg = rowptr[row];
  int end = rowptr[row + 1];
  float ax = 0.f, ay = 0.f, bx = 0.f, by = 0.f;
  int j = beg;
  for (; j + 3 < end; j += 4) {
    uint2 e0 = epack[j], e1 = epack[j + 1], e2 = epack[j + 2], e3 = epack[j + 3];
    uint2 ea = h ? e1 : e0;
    uint2 eb = h ? e3 : e2;
    __half2 ga = *(const __half2*)(Ein + (size_t)ea.x * 64 + 2 * p);
    __half2 gb = *(const __half2*)(Ein + (size_t)eb.x * 64 + 2 * p);
    float va = __uint_as_float(ea.y), vb = __uint_as_float(eb.y);
    float2 gaf = __half22float2(ga), gbf = __half22float2(gb);
    ax += va * gaf.x; ay += va * gaf.y;
    bx += vb * gbf.x; by += vb * gbf.y;
  }
  if (j + 1 < end) {
    uint2 e0 = epack[j], e1 = epack[j + 1];
    uint2 ea = h ? e1 : e0;
    __half2 ga = *(const __half2*)(Ein + (size_t)ea.x * 64 + 2 * p);
    float va = __uint_as_float(ea.y);
    float2 gaf = __half22float2(ga);
    ax += va * gaf.x; ay += va * gaf.y;
    j += 2;
  }
  if (j < end && h == 0) {
    uint2 e0 = epack[j];
    __half2 ga = *(const __half2*)(Ein + (size_t)e0.x * 64 + 2 * p);
    float va = __uint_as_float(e0.y);
    float2 gaf = __half22float2(ga);
    ax += va * gaf.x; ay += va * gaf.y;
  }
  float ox = ax + bx, oy = ay + by;
  ox += __shfl_xor(ox, 32, 64);
  oy += __shfl_xor(oy, 32, 64);
  if (h == 0) {
    float2* op = (float2*)(Oacc + (size_t)row * 64 + 2 * p);
    float2 cur = *op;
    *op = make_float2(cur.x + 0.25f * ox, cur.y + 0.25f * oy);
  }
}

// ---------------- weight transpose: uW1T[64][64] (for k_user) ---------------
__global__ __launch_bounds__(256) void k_wt(const float* __restrict__ uW1,
                                            float* __restrict__ WT) {
  int t = blockIdx.x * 256 + threadIdx.x;
  if (t < 4096) {
    int o = t >> 6, k = t & 63;
    WT[t] = uW1[k * 64 + o];
  }
}

// ---------------- pop-row precompute: hp[b]=p_b@gW1_p, pp1[b]=p_b@iW1 -------
__global__ __launch_bounds__(256) void k_pw(const float* __restrict__ pop,
                                            const float* __restrict__ gW1,
                                            const float* __restrict__ iW1,
                                            float* __restrict__ hp,
                                            float* __restrict__ pp1) {
  for (int idx = threadIdx.x; idx < 2 * POP_BINS * 64; idx += 256) {
    int q = idx;
    bool second = q >= POP_BINS * 64;
    if (second) q -= POP_BINS * 64;
    int b = q >> 6, o = q & 63;
    float s = 0.f;
    if (!second) {
      for (int k = 0; k < 64; k++) s += pop[b * 64 + k] * gW1[(64 + k) * 64 + o];
      hp[q] = s;
    } else {
      for (int k = 0; k < 64; k++) s += pop[b * 64 + k] * iW1[k * 64 + o];
      pp1[q] = s;
    }
  }
}

// ---------------- user MLP: thread per user, all state in VGPRs -------------
__global__ __launch_bounds__(64) void k_user(const float* __restrict__ Oacc,
                                             const int* __restrict__ users,
                                             const float* __restrict__ ubias,
                                             const float* __restrict__ uW1T,
                                             const float* __restrict__ ub1,
                                             const float* __restrict__ uW2,
                                             const float* __restrict__ ub2,
                                             float* __restrict__ Ut) {
  int b = blockIdx.x * 64 + threadIdx.x;
  int u = users[b];
  float x[64];
  const float4* xr = (const float4*)(Oacc + (size_t)u * 64);
#pragma unroll
  for (int q = 0; q < 16; q++) {
    float4 t4 = xr[q];
    x[4 * q] = t4.x; x[4 * q + 1] = t4.y; x[4 * q + 2] = t4.z; x[4 * q + 3] = t4.w;
  }
  float acc[64];
#pragma unroll
  for (int o2 = 0; o2 < 64; o2++) acc[o2] = ub2[o2];
#pragma unroll 1
  for (int o = 0; o < 64; o++) {
    const float* w = uW1T + o * 64;
    float a0 = ub1[o], a1 = 0.f, a2 = 0.f, a3 = 0.f;
#pragma unroll
    for (int k = 0; k < 64; k += 4) {
      a0 += x[k] * w[k]; a1 += x[k + 1] * w[k + 1];
      a2 += x[k + 2] * w[k + 2]; a3 += x[k + 3] * w[k + 3];
    }
    float hv = a0 + a1 + a2 + a3;
    hv = hv > 0.f ? hv : 0.f;
    const float* w2 = uW2 + o * 64;
#pragma unroll
    for (int o2 = 0; o2 < 64; o2++) acc[o2] += hv * w2[o2];
  }
#pragma unroll
  for (int o2 = 0; o2 < 64; o2++) Ut[o2 * 256 + b] = acc[o2];
  Ut[64 * 256 + b] = ubias[u];  // BIAS_SCALE = 1.0
}

// ---------------- GEMM1 fused with gate (G|T in regs -> z -> H1) ------------
__global__ __launch_bounds__(256) void k_gemm1z(const float* __restrict__ Oacc,
                                                const float* __restrict__ gW1,
                                                const float* __restrict__ iW1,
                                                const int* __restrict__ bins,
                                                const float* __restrict__ hp,
                                                const float* __restrict__ pp1,
                                                const float* __restrict__ gb1,
                                                const float* __restrict__ gW2,
                                                const float* __restrict__ gb2,
                                                const float* __restrict__ ib1,
                                                float* __restrict__ H1) {
  __shared__ float Is[64 * ST_P];
  __shared__ float Bs[64 * 128];
  __shared__ float zp[128][9];   // z partials, padded
  __shared__ float zs[128];      // final z per item
  int tid = threadIdx.x;
  int i0 = blockIdx.x * 128;
  {
    int c4 = tid & 15, r0 = tid >> 4;
#pragma unroll
    for (int s = 0; s < 8; s++) {
      int r = r0 + s * 16;
      int it = i0 + r;
      float4 v = make_float4(0.f, 0.f, 0.f, 0.f);
      if (it < N_ITEMS) v = *(const float4*)(Oacc + (size_t)(N_USERS + it) * 64 + c4 * 4);
      Is[(c4 * 4 + 0) * ST_P + r] = v.x;
      Is[(c4 * 4 + 1) * ST_P + r] = v.y;
      Is[(c4 * 4 + 2) * ST_P + r] = v.z;
      Is[(c4 * 4 + 3) * ST_P + r] = v.w;
    }
  }
  for (int idx = tid; idx < 64 * 128; idx += 256) {
    int k = idx >> 7, o = idx & 127;
    Bs[idx] = (o < 64) ? gW1[k * 64 + o] : iW1[k * 64 + (o - 64)];
  }
  __syncthreads();
  int tx = tid & 15, ty = tid >> 4;
  float acc[8][8];
#pragma unroll
  for (int a = 0; a < 8; a++)
#pragma unroll
    for (int b = 0; b < 8; b++) acc[a][b] = 0.f;
  const float* ip = Is + tx * 8;
  const float* wp = Bs + ty * 8;
#pragma unroll 2
  for (int k = 0; k < 64; k++) {
    float4 iv0 = *(const float4*)(ip + k * ST_P);
    float4 iv1 = *(const float4*)(ip + k * ST_P + 4);
    float4 wv0 = *(const float4*)(wp + k * 128);
    float4 wv1 = *(const float4*)(wp + k * 128 + 4);
    float iv[8] = {iv0.x, iv0.y, iv0.z, iv0.w, iv1.x, iv1.y, iv1.z, iv1.w};
    float wv[8] = {wv0.x, wv0.y, wv0.z, wv0.w, wv1.x, wv1.y, wv1.z, wv1.w};
#pragma unroll
    for (int a = 0; a < 8; a++)
#pragma unroll
      for (int b = 0; b < 8; b++) acc[a][b] += iv[a] * wv[b];
  }
  int ibase = i0 + tx * 8;
  // --- gate epilogue ---
  if (ty < 8) {  // G half: z partials over this thread's 8 o-columns
    int o0 = ty * 8;
#pragma unroll
    for (int a = 0; a < 8; a++) {
      int it = ibase + a;
      float p = 0.f;
      if (it < N_ITEMS) {
        int bin = bins[it];
        const float* hpr = hp + bin * 64 + o0;
#pragma unroll
        for (int b = 0; b < 8; b++) {
          float g = acc[a][b] + hpr[b] + gb1[o0 + b];
          g = g > 0.f ? g : 0.f;
          p += g * gW2[o0 + b];
        }
      }
      zp[tx * 8 + a][ty] = p;
    }
  }
  __syncthreads();
  if (tid < 128) {
    float s = gb2[0];
#pragma unroll
    for (int k = 0; k < 8; k++) s += zp[tid][k];
    zs[tid] = 1.f / (1.f + expf(-s));
  }
  __syncthreads();
  if (ty >= 8) {  // T half: fuse + relu -> H1
    int o0 = (ty - 8) * 8;
#pragma unroll
    for (int a = 0; a < 8; a++) {
      int it = ibase + a;
      if (it < N_ITEMS) {
        float z = zs[tx * 8 + a];
        int bin = bins[it];
        const float* ppr = pp1 + bin * 64 + o0;
        float h[8];
#pragma unroll
        for (int b = 0; b < 8; b++) {
          float v = (1.f - z) * acc[a][b] + z * ppr[b] + ib1[o0 + b];
          h[b] = v > 0.f ? v : 0.f;
        }
        *(float4*)(H1 + (size_t)it * 64 + o0) = make_float4(h[0], h[1], h[2], h[3]);
        *(float4*)(H1 + (size_t)it * 64 + o0 + 4) = make_float4(h[4], h[5], h[6], h[7]);
      }
    }
  }
}

// ---------------- GEMM2: I = H1 @ iW2 + ib2  (128x64 tile, K=64) ------------
__global__ __launch_bounds__(256) void k_gemm2(const float* __restrict__ H1,
                                               const float* __restrict__ iW2,
                                               const float* __restrict__ ib2,
                                               float* __restrict__ I) {
  __shared__ float Is[64 * ST_P];
  __shared__ float Bs[64 * 64];
  int tid = threadIdx.x;
  int i0 = blockIdx.x * 128;
  {
    int c4 = tid & 15, r0 = tid >> 4;
#pragma unroll
    for (int s = 0; s < 8; s++) {
      int r = r0 + s * 16;
      int it = i0 + r;
      float4 v = make_float4(0.f, 0.f, 0.f, 0.f);
      if (it < N_ITEMS) v = *(const float4*)(H1 + (size_t)it * 64 + c4 * 4);
      Is[(c4 * 4 + 0) * ST_P + r] = v.x;
      Is[(c4 * 4 + 1) * ST_P + r] = v.y;
      Is[(c4 * 4 + 2) * ST_P + r] = v.z;
      Is[(c4 * 4 + 3) * ST_P + r] = v.w;
    }
  }
  for (int idx = tid; idx < 64 * 64; idx += 256) Bs[idx] = iW2[idx];
  __syncthreads();
  int tx = tid & 15, ty = tid >> 4;
  float acc[8][4];
#pragma unroll
  for (int a = 0; a < 8; a++)
#pragma unroll
    for (int b = 0; b < 4; b++) acc[a][b] = 0.f;
  const float* ip = Is + tx * 8;
  const float* wp = Bs + ty * 4;
#pragma unroll 2
  for (int k = 0; k < 64; k++) {
    float4 iv0 = *(const float4*)(ip + k * ST_P);
    float4 iv1 = *(const float4*)(ip + k * ST_P + 4);
    float4 wv = *(const float4*)(wp + k * 64);
    float iv[8] = {iv0.x, iv0.y, iv0.z, iv0.w, iv1.x, iv1.y, iv1.z, iv1.w};
    float wvv[4] = {wv.x, wv.y, wv.z, wv.w};
#pragma unroll
    for (int a = 0; a < 8; a++)
#pragma unroll
      for (int b = 0; b < 4; b++) acc[a][b] += iv[a] * wvv[b];
  }
  int ibase = i0 + tx * 8;
  int oc = ty * 4;
  float b0 = ib2[oc], b1 = ib2[oc + 1], b2 = ib2[oc + 2], b3 = ib2[oc + 3];
#pragma unroll
  for (int a = 0; a < 8; a++) {
    int it = ibase + a;
    if (it < N_ITEMS) {
      float4 s0 = make_float4(acc[a][0] + b0, acc[a][1] + b1,
                              acc[a][2] + b2, acc[a][3] + b3);
      *(float4*)(I + (size_t)it * 64 + oc) = s0;
    }
  }
}

// ---------------- scores: 128x128 tile GEMM, 8x8 register blocking ----------
__global__ __launch_bounds__(256) void k_scores(const float* __restrict__ I,
                                                const float* __restrict__ Ut,
                                                const float* __restrict__ item_bias,
                                                float* __restrict__ out) {
  __shared__ float Is[64 * ST_P];
  __shared__ float Us[64 * 128];
  int tid = threadIdx.x;
  int i0 = blockIdx.x * 128;
  int ubase = blockIdx.y * 128;
  {
    int c4 = tid & 15, r0 = tid >> 4;
#pragma unroll
    for (int s = 0; s < 8; s++) {
      int r = r0 + s * 16;
      int it = i0 + r;
      float4 v = make_float4(0.f, 0.f, 0.f, 0.f);
      if (it < N_ITEMS) v = *(const float4*)(I + (size_t)it * 64 + c4 * 4);
      Is[(c4 * 4 + 0) * ST_P + r] = v.x;
      Is[(c4 * 4 + 1) * ST_P + r] = v.y;
      Is[(c4 * 4 + 2) * ST_P + r] = v.z;
      Is[(c4 * 4 + 3) * ST_P + r] = v.w;
    }
  }
  {
    int u4 = tid & 31, k0 = tid >> 5;
#pragma unroll
    for (int s = 0; s < 8; s++) {
      int k = k0 + s * 8;
      float4 v = *(const float4*)(Ut + k * 256 + ubase + u4 * 4);
      *(float4*)(Us + k * 128 + u4 * 4) = v;
    }
  }
  __syncthreads();
  int tx = tid & 15;
  int ty = tid >> 4;
  float acc[8][8];
#pragma unroll
  for (int a = 0; a < 8; a++)
#pragma unroll
    for (int b = 0; b < 8; b++) acc[a][b] = 0.f;
  const float* ip = Is + tx * 8;
  const float* up = Us + ty * 8;
#pragma unroll 2
  for (int k = 0; k < 64; k++) {
    float4 iv0 = *(const float4*)(ip + k * ST_P);
    float4 iv1 = *(const float4*)(ip + k * ST_P + 4);
    float4 uv0 = *(const float4*)(up + k * 128);
    float4 uv1 = *(const float4*)(up + k * 128 + 4);
    float iv[8] = {iv0.x, iv0.y, iv0.z, iv0.w, iv1.x, iv1.y, iv1.z, iv1.w};
    float uv[8] = {uv0.x, uv0.y, uv0.z, uv0.w, uv1.x, uv1.y, uv1.z, uv1.w};
#pragma unroll
    for (int a = 0; a < 8; a++)
#pragma unroll
      for (int b = 0; b < 8; b++) acc[a][b] += iv[a] * uv[b];
  }
  int ibase = i0 + tx * 8;
  float ib[8];
#pragma unroll
  for (int a = 0; a < 8; a++)
    ib[a] = (ibase + a < N_ITEMS) ? item_bias[ibase + a] : 0.f;
#pragma unroll
  for (int bb = 0; bb < 8; bb++) {
    int bu = ubase + ty * 8 + bb;
    float ubias = Ut[64 * 256 + bu];
    float* orow = out + (size_t)bu * N_ITEMS + ibase;
    if (ibase + 7 < N_ITEMS) {
      float4 s0 = make_float4(acc[0][bb] + ubias + ib[0], acc[1][bb] + ubias + ib[1],
                              acc[2][bb] + ubias + ib[2], acc[3][bb] + ubias + ib[3]);
      float4 s1 = make_float4(acc[4][bb] + ubias + ib[4], acc[5][bb] + ubias + ib[5],
                              acc[6][bb] + ubias + ib[6], acc[7][bb] + ubias + ib[7]);
      *(float4*)orow = s0;
      *(float4*)(orow + 4) = s1;
    } else {
#pragma unroll
      for (int a = 0; a < 8; a++)
        if (ibase + a < N_ITEMS) orow[a] = acc[a][bb] + ubias + ib[a];
    }
  }
}

extern "C" void kernel_launch(void* const* d_in, const int* in_sizes, int n_in,
                              void* d_out, int out_size, void* d_ws, size_t ws_size,
                              hipStream_t stream) {
  const float* user_emb  = (const float*)d_in[0];
  const float* item_emb  = (const float*)d_in[1];
  const float* user_bias = (const float*)d_in[2];
  const float* item_bias = (const float*)d_in[3];
  const float* pop_emb   = (const float*)d_in[4];
  const float* uW1 = (const float*)d_in[5];
  const float* ub1 = (const float*)d_in[6];
  const float* uW2 = (const float*)d_in[7];
  const float* ub2 = (const float*)d_in[8];
  const float* iW1 = (const float*)d_in[9];
  const float* ib1 = (const float*)d_in[10];
  const float* iW2 = (const float*)d_in[11];
  const float* ib2 = (const float*)d_in[12];
  const float* gW1 = (const float*)d_in[13];
  const float* gb1 = (const float*)d_in[14];
  const float* gW2 = (const float*)d_in[15];
  const float* gb2 = (const float*)d_in[16];
  const float* adj_vals = (const float*)d_in[17];
  const int* adj_rows = (const int*)d_in[18];
  const int* adj_cols = (const int*)d_in[19];
  const int* bins  = (const int*)d_in[20];
  const int* users = (const int*)d_in[21];
  float* out = (float*)d_out;

  // workspace layout (float offsets); total ~132.7 MB
  // rowptr spans [32800000, 32950001); uflag AFTER it.
  float* ws = (float*)d_ws;
  float* Oacc = ws;                    // 9,600,000
  float* bufA = ws + 9600000;          // 9,600,000
  float* bufB = ws + 19200000;         // 9,600,000 (gstage pre-spmm)
  uint2* epack = (uint2*)(ws + 28800000);      // 2,000,000 * 8B -> ends 32800000
  int* rowptr = (int*)(ws + 32800000);         // 150,001 ints -> ends 32950001
  int* uflag  = (int*)(ws + 32960000);         // 100,000 ints -> ends 33060000
  int* ucnt   = (int*)(ws + 33060000);         // 1 (uflag+100000: one memset)
  int* ulist  = (int*)(ws + 33061000);         // 256
  float* Ut   = ws + 33130000;                 // 65*256
  float* WT   = ws + 33150000;                 // 4,096 (uW1T)
  float* hp   = ws + 33160000;                 // 640
  float* pp1  = ws + 33161000;                 // 640
  int* bcur   = (int*)(ws + 33170000);         // 293
  uint2* gstage = (uint2*)bufB;
  // fp16 E-tables (19.2 MB = 4.8M floats each):
  __half* Eh0 = (__half*)bufA;                 // emb table; dead after spmm1
  __half* E1h = (__half*)(bufA + 4800000);     // layer1 out; dead after spmm2
  __half* E2h = (__half*)bufB;                 // layer2 out (gstage dead); dead after spmm3
  float* H1 = bufA + 6400000;                  // 3,200,000 (E1h dead by then)
  float* I  = bufB;                            // 3,200,000 (E2h dead by then)
  const float* uW1T = WT;

  hipMemsetAsync(bcur, 0, NB2 * sizeof(int), stream);
  hipMemsetAsync(uflag, 0, 100001 * sizeof(int), stream);  // covers uflag+ucnt
  k_cvt<<<9375, 256, 0, stream>>>(user_emb, item_emb, Eh0);
  k_bcount<<<P1_BLOCKS, 256, 0, stream>>>(adj_rows, bcur);
  k_bscan<<<1, 512, 0, stream>>>(bcur);
  k_p1<<<P1_BLOCKS, 256, 0, stream>>>(adj_rows, adj_cols, adj_vals, bcur, gstage);
  k_p2<<<NB2, 256, 0, stream>>>(bcur, gstage, epack, rowptr);
  k_flags<<<1, 256, 0, stream>>>(users, uflag, ulist, ucnt);

  k_spmm1<<<37500, 256, 0, stream>>>(rowptr, epack, user_emb, item_emb, Eh0, uflag, E1h, Oacc);
  k_spmm2h<<<37500, 256, 0, stream>>>(rowptr, epack, E1h, uflag, E2h, Oacc);
  k_spmm3h<<<12564, 256, 0, stream>>>(rowptr, epack, E2h, ulist, ucnt, Oacc);

  k_wt<<<16, 256, 0, stream>>>(uW1, WT);
  k_pw<<<1, 256, 0, stream>>>(pop_emb, gW1, iW1, hp, pp1);
  k_user<<<4, 64, 0, stream>>>(Oacc, users, user_bias, uW1T, ub1, uW2, ub2, Ut);
  k_gemm1z<<<391, 256, 0, stream>>>(Oacc, gW1, iW1, bins, hp, pp1, gb1, gW2, gb2, ib1, H1);
  k_gemm2<<<391, 256, 0, stream>>>(H1, iW2, ib2, I);
  k_scores<<<dim3(391, 2), 256, 0, stream>>>(I, Ut, item_bias, out);
}

// Round 5
// 554.677 us; speedup vs baseline: 1.2112x; 1.0156x over previous
//
#include <hip/hip_runtime.h>
#include <hip/hip_fp16.h>

#define N_USERS 100000
#define N_ITEMS 50000
#define N_NODES 150000
#define D 64
#define NNZ 2000000
#define BATCH 256
#define POP_BINS 10

// bucketed CSR params
#define BSH 9
#define NB2 293            // ceil(150000/512)
#define CAP 8192           // max edges per bucket (mean 6827, sigma ~82)
#define P1_EPB 4096        // edges per block in pass 1
#define P1_BLOCKS 489      // ceil(NNZ/P1_EPB)

#define ST_P 130           // I-tile LDS pad for transposed stages

// ---------------- bucket count: LDS histogram -> global ----------------------
__global__ __launch_bounds__(256) void k_bcount(const int* __restrict__ rows,
                                                int* __restrict__ bcnt) {
  __shared__ int c[NB2];
  int t = threadIdx.x;
  for (int i = t; i < NB2; i += 256) c[i] = 0;
  __syncthreads();
  int base = blockIdx.x * P1_EPB;
  for (int i = 0; i < 16; i++) {
    int e = base + i * 256 + t;
    if (e < NNZ) atomicAdd(&c[rows[e] >> BSH], 1);
  }
  __syncthreads();
  for (int i = t; i < NB2; i += 256)
    if (c[i]) atomicAdd(&bcnt[i], c[i]);
}

// ---------------- bucket scan: exclusive, in-place (becomes bcur) ------------
__global__ __launch_bounds__(512) void k_bscan(int* __restrict__ bcnt) {
  __shared__ int s[512];
  int t = threadIdx.x;
  int v = (t < NB2) ? bcnt[t] : 0;
  s[t] = v;
  __syncthreads();
  for (int o = 1; o < 512; o <<= 1) {
    int x = (t >= o) ? s[t - o] : 0;
    __syncthreads();
    s[t] += x;
    __syncthreads();
  }
  if (t < NB2) bcnt[t] = s[t] - v;  // exclusive base; p1 advances to inclusive
}

// ---------------- pass 1: bucket edges, TWO-PASS (no per-thread arrays) -----
__global__ __launch_bounds__(256) void k_p1(const int* __restrict__ rows,
                                            const int* __restrict__ cols,
                                            const float* __restrict__ vals,
                                            int* __restrict__ bcur,
                                            uint2* __restrict__ gstage) {
  __shared__ int cnt[NB2];
  __shared__ int gbase[NB2];
  int t = threadIdx.x;
  for (int i = t; i < NB2; i += 256) cnt[i] = 0;
  __syncthreads();
  int base = blockIdx.x * P1_EPB;
  // pass A: count buckets
  for (int i = 0; i < 16; i++) {
    int e = base + i * 256 + t;
    if (e < NNZ) atomicAdd(&cnt[rows[e] >> BSH], 1);
  }
  __syncthreads();
  for (int i = t; i < NB2; i += 256) {
    int c = cnt[i];
    gbase[i] = c ? atomicAdd(&bcur[i], c) : 0;
    cnt[i] = 0;
  }
  __syncthreads();
  // pass B: re-read (L2-hot) and scatter clustered
  for (int i = 0; i < 16; i++) {
    int e = base + i * 256 + t;
    if (e < NNZ) {
      int r = rows[e];
      int b = r >> BSH;
      int rank = atomicAdd(&cnt[b], 1);
      unsigned key = ((unsigned)(r & 511) << 18) | (unsigned)cols[e];
      gstage[gbase[b] + rank] = make_uint2(key, __float_as_uint(vals[e]));
    }
  }
}

// ---------------- pass 2: per-bucket LDS counting sort, contiguous writes ---
// Also produces rowptr (bucketbase + local exclusive scan).
__global__ __launch_bounds__(256) void k_p2(const int* __restrict__ bcur,
                                            const uint2* __restrict__ gstage,
                                            uint2* __restrict__ epack,
                                            int* __restrict__ rowptr) {
  __shared__ int cnt[512];
  __shared__ int off[512];
  __shared__ int s[256];
  __shared__ uint2 buf[CAP];
  int b = blockIdx.x, t = threadIdx.x;
  int base = (b == 0) ? 0 : bcur[b - 1];  // post-p1 bcur = inclusive scan
  int end = bcur[b];
  int n = end - base;
  cnt[t] = 0;
  cnt[t + 256] = 0;
  __syncthreads();
  for (int j = t; j < n; j += 256)
    atomicAdd(&cnt[gstage[base + j].x >> 18], 1);
  __syncthreads();
  // scan 512 entries (each thread owns 2)
  int c0 = cnt[2 * t], c1 = cnt[2 * t + 1];
  s[t] = c0 + c1;
  __syncthreads();
  for (int o = 1; o < 256; o <<= 1) {
    int x = (t >= o) ? s[t - o] : 0;
    __syncthreads();
    s[t] += x;
    __syncthreads();
  }
  int ex = t ? s[t - 1] : 0;
  off[2 * t] = ex;
  off[2 * t + 1] = ex + c0;
  int gr = (b << BSH) + 2 * t;
  if (gr < N_NODES) rowptr[gr] = base + ex;
  if (gr + 1 < N_NODES) rowptr[gr + 1] = base + ex + c0;
  if (b == NB2 - 1 && t == 0) rowptr[N_NODES] = NNZ;
  __syncthreads();
  for (int j = t; j < n; j += 256) {
    uint2 ed = gstage[base + j];
    int lr = ed.x >> 18;
    int pos = atomicAdd(&off[lr], 1);
    buf[pos] = make_uint2(ed.x & 0x3FFFFu, ed.y);
  }
  __syncthreads();
  for (int j = t; j < n; j += 256) epack[base + j] = buf[j];
}

// ---------------- batch-user flags + unique list ----------------------------
__global__ __launch_bounds__(256) void k_flags(const int* __restrict__ users,
                                               int* __restrict__ uflag,
                                               int* __restrict__ ulist,
                                               int* __restrict__ ucnt) {
  int u = users[threadIdx.x];
  if (atomicExch(&uflag[u], 1) == 0) {
    int p = atomicAdd(ucnt, 1);
    ulist[p] = u;
  }
}

// ---------------- emb -> fp16 combined table --------------------------------
__global__ __launch_bounds__(256) void k_cvt(const float* __restrict__ ue,
                                             const float* __restrict__ ie,
                                             __half* __restrict__ Eh) {
  int t = blockIdx.x * 256 + threadIdx.x;     // float4 index, < 2,400,000
  if (t >= 2400000) return;
  size_t fo = (size_t)t * 4;
  const float* src = (fo < (size_t)N_USERS * 64) ? ue + fo
                                                 : ie + (fo - (size_t)N_USERS * 64);
  float4 v = *(const float4*)src;
  __half2* dst = (__half2*)(Eh + fo);
  dst[0] = __floats2half2_rn(v.x, v.y);
  dst[1] = __floats2half2_rn(v.z, v.w);
}

// ============ quarter-wave SPMM core ========================================
// lane = 16*q + p (q in 0..3, p in 0..15). Quarter-wave q handles edge j+q;
// lane loads its OWN descriptor epack[j+q] (4 consecutive uint2 -> 1 line,
// no cndmask selects) and one 8B half4 gather covering cols {4p..4p+3}.
// One wave request = 4 edges. Tail: clamp descriptor to end-1 (same lines as
// the last valid quarter -> no extra lines/requests), val zeroed.
#define SPMM_QW_BODY(TBL)                                                     \
  float a0 = 0.f, a1 = 0.f, a2 = 0.f, a3 = 0.f;                               \
  int j = beg;                                                                \
  for (; j + 7 < end; j += 8) {                                               \
    uint2 ea = epack[j + q];                                                  \
    uint2 eb = epack[j + 4 + q];                                              \
    uint2 ra = *(const uint2*)(TBL + (size_t)ea.x * 64 + 4 * p);              \
    uint2 rb = *(const uint2*)(TBL + (size_t)eb.x * 64 + 4 * p);              \
    float va = __uint_as_float(ea.y), vb = __uint_as_float(eb.y);             \
    float2 la = __half22float2(*(const __half2*)&ra.x);                       \
    float2 ha = __half22float2(*(const __half2*)&ra.y);                       \
    float2 lb = __half22float2(*(const __half2*)&rb.x);                       \
    float2 hb = __half22float2(*(const __half2*)&rb.y);                       \
    a0 += va * la.x; a1 += va * la.y; a2 += va * ha.x; a3 += va * ha.y;       \
    a0 += vb * lb.x; a1 += vb * lb.y; a2 += vb * hb.x; a3 += vb * hb.y;       \
  }                                                                           \
  for (; j < end; j += 4) {                                                   \
    int jj = j + q;                                                           \
    int jc = (jj < end) ? jj : end - 1;                                       \
    uint2 e = epack[jc];                                                      \
    float v = (jj < end) ? __uint_as_float(e.y) : 0.f;                        \
    uint2 r = *(const uint2*)(TBL + (size_t)e.x * 64 + 4 * p);                \
    float2 l = __half22float2(*(const __half2*)&r.x);                         \
    float2 h2 = __half22float2(*(const __half2*)&r.y);                        \
    a0 += v * l.x; a1 += v * l.y; a2 += v * h2.x; a3 += v * h2.y;             \
  }                                                                           \
  a0 += __shfl_xor(a0, 16, 64); a0 += __shfl_xor(a0, 32, 64);                 \
  a1 += __shfl_xor(a1, 16, 64); a1 += __shfl_xor(a1, 32, 64);                 \
  a2 += __shfl_xor(a2, 16, 64); a2 += __shfl_xor(a2, 32, 64);                 \
  a3 += __shfl_xor(a3, 16, 64); a3 += __shfl_xor(a3, 32, 64);

// ---------------- SPMM layer 1 ----------------------------------------------
__global__ __launch_bounds__(256) void k_spmm1(const int* __restrict__ rowptr,
                                               const uint2* __restrict__ epack,
                                               const float* __restrict__ ue,
                                               const float* __restrict__ ie,
                                               const __half* __restrict__ Eh0,
                                               const int* __restrict__ uflag,
                                               __half* __restrict__ EoutH,
                                               float* __restrict__ Oacc) {
  int wave = blockIdx.x * 4 + (threadIdx.x >> 6);
  int row = __builtin_amdgcn_readfirstlane(wave);
  if (row >= N_NODES) return;
  int lane = threadIdx.x & 63;
  int p = lane & 15, q = lane >> 4;
  int beg = rowptr[row];
  int end = rowptr[row + 1];
  SPMM_QW_BODY(Eh0)
  if (q == 0) {
    __half2* eo = (__half2*)(EoutH + (size_t)row * 64 + 4 * p);
    eo[0] = __floats2half2_rn(a0, a1);
    eo[1] = __floats2half2_rn(a2, a3);
    bool need = (row >= N_USERS) || (uflag[row] != 0);
    if (need) {
      const float* srow = (row < N_USERS) ? ue + (size_t)row * 64
                                          : ie + (size_t)(row - N_USERS) * 64;
      float4 sv = *(const float4*)(srow + 4 * p);
      *(float4*)(Oacc + (size_t)row * 64 + 4 * p) =
          make_float4(0.25f * (sv.x + a0), 0.25f * (sv.y + a1),
                      0.25f * (sv.z + a2), 0.25f * (sv.w + a3));
    }
  }
}

// ---------------- SPMM layer 2 ----------------------------------------------
__global__ __launch_bounds__(256) void k_spmm2h(const int* __restrict__ rowptr,
                                                const uint2* __restrict__ epack,
                                                const __half* __restrict__ Ein,
                                                const int* __restrict__ uflag,
                                                __half* __restrict__ EoutH,
                                                float* __restrict__ Oacc) {
  int wave = blockIdx.x * 4 + (threadIdx.x >> 6);
  int row = __builtin_amdgcn_readfirstlane(wave);
  if (row >= N_NODES) return;
  int lane = threadIdx.x & 63;
  int p = lane & 15, q = lane >> 4;
  int beg = rowptr[row];
  int end = rowptr[row + 1];
  SPMM_QW_BODY(Ein)
  if (q == 0) {
    __half2* eo = (__half2*)(EoutH + (size_t)row * 64 + 4 * p);
    eo[0] = __floats2half2_rn(a0, a1);
    eo[1] = __floats2half2_rn(a2, a3);
    if (row >= N_USERS || uflag[row] != 0) {
      float4* op = (float4*)(Oacc + (size_t)row * 64 + 4 * p);
      float4 cur = *op;
      *op = make_float4(cur.x + 0.25f * a0, cur.y + 0.25f * a1,
                        cur.z + 0.25f * a2, cur.w + 0.25f * a3);
    }
  }
}

// ---------------- SPMM layer 3: only needed rows ----------------------------
__global__ __launch_bounds__(256) void k_spmm3h(const int* __restrict__ rowptr,
                                                const uint2* __restrict__ epack,
                                                const __half* __restrict__ Ein,
                                                const int* __restrict__ ulist,
                                                const int* __restrict__ ucnt,
                                                float* __restrict__ Oacc) {
  int w = blockIdx.x * 4 + (threadIdx.x >> 6);
  int row;
  if (w < N_ITEMS) {
    row = N_USERS + w;
  } else {
    int k = w - N_ITEMS;
    if (k >= ucnt[0]) return;
    row = ulist[k];
  }
  row = __builtin_amdgcn_readfirstlane(row);
  int lane = threadIdx.x & 63;
  int p = lane & 15, q = lane >> 4;
  int beg = rowptr[row];
  int end = rowptr[row + 1];
  SPMM_QW_BODY(Ein)
  if (q == 0) {
    float4* op = (float4*)(Oacc + (size_t)row * 64 + 4 * p);
    float4 cur = *op;
    *op = make_float4(cur.x + 0.25f * a0, cur.y + 0.25f * a1,
                      cur.z + 0.25f * a2, cur.w + 0.25f * a3);
  }
}

// ---------------- weight transpose: uW1T[64][64] (for k_user) ---------------
__global__ __launch_bounds__(256) void k_wt(const float* __restrict__ uW1,
                                            float* __restrict__ WT) {
  int t = blockIdx.x * 256 + threadIdx.x;
  if (t < 4096) {
    int o = t >> 6, k = t & 63;
    WT[t] = uW1[k * 64 + o];
  }
}

// ---------------- pop-row precompute: hp[b]=p_b@gW1_p, pp1[b]=p_b@iW1 -------
__global__ __launch_bounds__(256) void k_pw(const float* __restrict__ pop,
                                            const float* __restrict__ gW1,
                                            const float* __restrict__ iW1,
                                            float* __restrict__ hp,
                                            float* __restrict__ pp1) {
  for (int idx = threadIdx.x; idx < 2 * POP_BINS * 64; idx += 256) {
    int q = idx;
    bool second = q >= POP_BINS * 64;
    if (second) q -= POP_BINS * 64;
    int b = q >> 6, o = q & 63;
    float s = 0.f;
    if (!second) {
      for (int k = 0; k < 64; k++) s += pop[b * 64 + k] * gW1[(64 + k) * 64 + o];
      hp[q] = s;
    } else {
      for (int k = 0; k < 64; k++) s += pop[b * 64 + k] * iW1[k * 64 + o];
      pp1[q] = s;
    }
  }
}

// ---------------- user MLP: thread per user, all state in VGPRs -------------
__global__ __launch_bounds__(64) void k_user(const float* __restrict__ Oacc,
                                             const int* __restrict__ users,
                                             const float* __restrict__ ubias,
                                             const float* __restrict__ uW1T,
                                             const float* __restrict__ ub1,
                                             const float* __restrict__ uW2,
                                             const float* __restrict__ ub2,
                                             float* __restrict__ Ut) {
  int b = blockIdx.x * 64 + threadIdx.x;
  int u = users[b];
  float x[64];
  const float4* xr = (const float4*)(Oacc + (size_t)u * 64);
#pragma unroll
  for (int q = 0; q < 16; q++) {
    float4 t4 = xr[q];
    x[4 * q] = t4.x; x[4 * q + 1] = t4.y; x[4 * q + 2] = t4.z; x[4 * q + 3] = t4.w;
  }
  float acc[64];
#pragma unroll
  for (int o2 = 0; o2 < 64; o2++) acc[o2] = ub2[o2];
#pragma unroll 1
  for (int o = 0; o < 64; o++) {
    const float* w = uW1T + o * 64;
    float a0 = ub1[o], a1 = 0.f, a2 = 0.f, a3 = 0.f;
#pragma unroll
    for (int k = 0; k < 64; k += 4) {
      a0 += x[k] * w[k]; a1 += x[k + 1] * w[k + 1];
      a2 += x[k + 2] * w[k + 2]; a3 += x[k + 3] * w[k + 3];
    }
    float hv = a0 + a1 + a2 + a3;
    hv = hv > 0.f ? hv : 0.f;
    const float* w2 = uW2 + o * 64;
#pragma unroll
    for (int o2 = 0; o2 < 64; o2++) acc[o2] += hv * w2[o2];
  }
#pragma unroll
  for (int o2 = 0; o2 < 64; o2++) Ut[o2 * 256 + b] = acc[o2];
  Ut[64 * 256 + b] = ubias[u];  // BIAS_SCALE = 1.0
}

// ---------------- GEMM1 fused with gate (G|T in regs -> z -> H1) ------------
__global__ __launch_bounds__(256) void k_gemm1z(const float* __restrict__ Oacc,
                                                const float* __restrict__ gW1,
                                                const float* __restrict__ iW1,
                                                const int* __restrict__ bins,
                                                const float* __restrict__ hp,
                                                const float* __restrict__ pp1,
                                                const float* __restrict__ gb1,
                                                const float* __restrict__ gW2,
                                                const float* __restrict__ gb2,
                                                const float* __restrict__ ib1,
                                                float* __restrict__ H1) {
  __shared__ float Is[64 * ST_P];
  __shared__ float Bs[64 * 128];
  __shared__ float zp[128][9];   // z partials, padded
  __shared__ float zs[128];      // final z per item
  int tid = threadIdx.x;
  int i0 = blockIdx.x * 128;
  {
    int c4 = tid & 15, r0 = tid >> 4;
#pragma unroll
    for (int s = 0; s < 8; s++) {
      int r = r0 + s * 16;
      int it = i0 + r;
      float4 v = make_float4(0.f, 0.f, 0.f, 0.f);
      if (it < N_ITEMS) v = *(const float4*)(Oacc + (size_t)(N_USERS + it) * 64 + c4 * 4);
      Is[(c4 * 4 + 0) * ST_P + r] = v.x;
      Is[(c4 * 4 + 1) * ST_P + r] = v.y;
      Is[(c4 * 4 + 2) * ST_P + r] = v.z;
      Is[(c4 * 4 + 3) * ST_P + r] = v.w;
    }
  }
  for (int idx = tid; idx < 64 * 128; idx += 256) {
    int k = idx >> 7, o = idx & 127;
    Bs[idx] = (o < 64) ? gW1[k * 64 + o] : iW1[k * 64 + (o - 64)];
  }
  __syncthreads();
  int tx = tid & 15, ty = tid >> 4;
  float acc[8][8];
#pragma unroll
  for (int a = 0; a < 8; a++)
#pragma unroll
    for (int b = 0; b < 8; b++) acc[a][b] = 0.f;
  const float* ip = Is + tx * 8;
  const float* wp = Bs + ty * 8;
#pragma unroll 2
  for (int k = 0; k < 64; k++) {
    float4 iv0 = *(const float4*)(ip + k * ST_P);
    float4 iv1 = *(const float4*)(ip + k * ST_P + 4);
    float4 wv0 = *(const float4*)(wp + k * 128);
    float4 wv1 = *(const float4*)(wp + k * 128 + 4);
    float iv[8] = {iv0.x, iv0.y, iv0.z, iv0.w, iv1.x, iv1.y, iv1.z, iv1.w};
    float wv[8] = {wv0.x, wv0.y, wv0.z, wv0.w, wv1.x, wv1.y, wv1.z, wv1.w};
#pragma unroll
    for (int a = 0; a < 8; a++)
#pragma unroll
      for (int b = 0; b < 8; b++) acc[a][b] += iv[a] * wv[b];
  }
  int ibase = i0 + tx * 8;
  // --- gate epilogue ---
  if (ty < 8) {  // G half: z partials over this thread's 8 o-columns
    int o0 = ty * 8;
#pragma unroll
    for (int a = 0; a < 8; a++) {
      int it = ibase + a;
      float p = 0.f;
      if (it < N_ITEMS) {
        int bin = bins[it];
        const float* hpr = hp + bin * 64 + o0;
#pragma unroll
        for (int b = 0; b < 8; b++) {
          float g = acc[a][b] + hpr[b] + gb1[o0 + b];
          g = g > 0.f ? g : 0.f;
          p += g * gW2[o0 + b];
        }
      }
      zp[tx * 8 + a][ty] = p;
    }
  }
  __syncthreads();
  if (tid < 128) {
    float s = gb2[0];
#pragma unroll
    for (int k = 0; k < 8; k++) s += zp[tid][k];
    zs[tid] = 1.f / (1.f + expf(-s));
  }
  __syncthreads();
  if (ty >= 8) {  // T half: fuse + relu -> H1
    int o0 = (ty - 8) * 8;
#pragma unroll
    for (int a = 0; a < 8; a++) {
      int it = ibase + a;
      if (it < N_ITEMS) {
        float z = zs[tx * 8 + a];
        int bin = bins[it];
        const float* ppr = pp1 + bin * 64 + o0;
        float h[8];
#pragma unroll
        for (int b = 0; b < 8; b++) {
          float v = (1.f - z) * acc[a][b] + z * ppr[b] + ib1[o0 + b];
          h[b] = v > 0.f ? v : 0.f;
        }
        *(float4*)(H1 + (size_t)it * 64 + o0) = make_float4(h[0], h[1], h[2], h[3]);
        *(float4*)(H1 + (size_t)it * 64 + o0 + 4) = make_float4(h[4], h[5], h[6], h[7]);
      }
    }
  }
}

// ---------------- GEMM2: I = H1 @ iW2 + ib2  (128x64 tile, K=64) ------------
__global__ __launch_bounds__(256) void k_gemm2(const float* __restrict__ H1,
                                               const float* __restrict__ iW2,
                                               const float* __restrict__ ib2,
                                               float* __restrict__ I) {
  __shared__ float Is[64 * ST_P];
  __shared__ float Bs[64 * 64];
  int tid = threadIdx.x;
  int i0 = blockIdx.x * 128;
  {
    int c4 = tid & 15, r0 = tid >> 4;
#pragma unroll
    for (int s = 0; s < 8; s++) {
      int r = r0 + s * 16;
      int it = i0 + r;
      float4 v = make_float4(0.f, 0.f, 0.f, 0.f);
      if (it < N_ITEMS) v = *(const float4*)(H1 + (size_t)it * 64 + c4 * 4);
      Is[(c4 * 4 + 0) * ST_P + r] = v.x;
      Is[(c4 * 4 + 1) * ST_P + r] = v.y;
      Is[(c4 * 4 + 2) * ST_P + r] = v.z;
      Is[(c4 * 4 + 3) * ST_P + r] = v.w;
    }
  }
  for (int idx = tid; idx < 64 * 64; idx += 256) Bs[idx] = iW2[idx];
  __syncthreads();
  int tx = tid & 15, ty = tid >> 4;
  float acc[8][4];
#pragma unroll
  for (int a = 0; a < 8; a++)
#pragma unroll
    for (int b = 0; b < 4; b++) acc[a][b] = 0.f;
  const float* ip = Is + tx * 8;
  const float* wp = Bs + ty * 4;
#pragma unroll 2
  for (int k = 0; k < 64; k++) {
    float4 iv0 = *(const float4*)(ip + k * ST_P);
    float4 iv1 = *(const float4*)(ip + k * ST_P + 4);
    float4 wv = *(const float4*)(wp + k * 64);
    float iv[8] = {iv0.x, iv0.y, iv0.z, iv0.w, iv1.x, iv1.y, iv1.z, iv1.w};
    float wvv[4] = {wv.x, wv.y, wv.z, wv.w};
#pragma unroll
    for (int a = 0; a < 8; a++)
#pragma unroll
      for (int b = 0; b < 4; b++) acc[a][b] += iv[a] * wvv[b];
  }
  int ibase = i0 + tx * 8;
  int oc = ty * 4;
  float b0 = ib2[oc], b1 = ib2[oc + 1], b2 = ib2[oc + 2], b3 = ib2[oc + 3];
#pragma unroll
  for (int a = 0; a < 8; a++) {
    int it = ibase + a;
    if (it < N_ITEMS) {
      float4 s0 = make_float4(acc[a][0] + b0, acc[a][1] + b1,
                              acc[a][2] + b2, acc[a][3] + b3);
      *(float4*)(I + (size_t)it * 64 + oc) = s0;
    }
  }
}

// ---------------- scores: 128x128 tile GEMM, 8x8 register blocking ----------
__global__ __launch_bounds__(256) void k_scores(const float* __restrict__ I,
                                                const float* __restrict__ Ut,
                                                const float* __restrict__ item_bias,
                                                float* __restrict__ out) {
  __shared__ float Is[64 * ST_P];
  __shared__ float Us[64 * 128];
  int tid = threadIdx.x;
  int i0 = blockIdx.x * 128;
  int ubase = blockIdx.y * 128;
  {
    int c4 = tid & 15, r0 = tid >> 4;
#pragma unroll
    for (int s = 0; s < 8; s++) {
      int r = r0 + s * 16;
      int it = i0 + r;
      float4 v = make_float4(0.f, 0.f, 0.f, 0.f);
      if (it < N_ITEMS) v = *(const float4*)(I + (size_t)it * 64 + c4 * 4);
      Is[(c4 * 4 + 0) * ST_P + r] = v.x;
      Is[(c4 * 4 + 1) * ST_P + r] = v.y;
      Is[(c4 * 4 + 2) * ST_P + r] = v.z;
      Is[(c4 * 4 + 3) * ST_P + r] = v.w;
    }
  }
  {
    int u4 = tid & 31, k0 = tid >> 5;
#pragma unroll
    for (int s = 0; s < 8; s++) {
      int k = k0 + s * 8;
      float4 v = *(const float4*)(Ut + k * 256 + ubase + u4 * 4);
      *(float4*)(Us + k * 128 + u4 * 4) = v;
    }
  }
  __syncthreads();
  int tx = tid & 15;
  int ty = tid >> 4;
  float acc[8][8];
#pragma unroll
  for (int a = 0; a < 8; a++)
#pragma unroll
    for (int b = 0; b < 8; b++) acc[a][b] = 0.f;
  const float* ip = Is + tx * 8;
  const float* up = Us + ty * 8;
#pragma unroll 2
  for (int k = 0; k < 64; k++) {
    float4 iv0 = *(const float4*)(ip + k * ST_P);
    float4 iv1 = *(const float4*)(ip + k * ST_P + 4);
    float4 uv0 = *(const float4*)(up + k * 128);
    float4 uv1 = *(const float4*)(up + k * 128 + 4);
    float iv[8] = {iv0.x, iv0.y, iv0.z, iv0.w, iv1.x, iv1.y, iv1.z, iv1.w};
    float uv[8] = {uv0.x, uv0.y, uv0.z, uv0.w, uv1.x, uv1.y, uv1.z, uv1.w};
#pragma unroll
    for (int a = 0; a < 8; a++)
#pragma unroll
      for (int b = 0; b < 8; b++) acc[a][b] += iv[a] * uv[b];
  }
  int ibase = i0 + tx * 8;
  float ib[8];
#pragma unroll
  for (int a = 0; a < 8; a++)
    ib[a] = (ibase + a < N_ITEMS) ? item_bias[ibase + a] : 0.f;
#pragma unroll
  for (int bb = 0; bb < 8; bb++) {
    int bu = ubase + ty * 8 + bb;
    float ubias = Ut[64 * 256 + bu];
    float* orow = out + (size_t)bu * N_ITEMS + ibase;
    if (ibase + 7 < N_ITEMS) {
      float4 s0 = make_float4(acc[0][bb] + ubias + ib[0], acc[1][bb] + ubias + ib[1],
                              acc[2][bb] + ubias + ib[2], acc[3][bb] + ubias + ib[3]);
      float4 s1 = make_float4(acc[4][bb] + ubias + ib[4], acc[5][bb] + ubias + ib[5],
                              acc[6][bb] + ubias + ib[6], acc[7][bb] + ubias + ib[7]);
      *(float4*)orow = s0;
      *(float4*)(orow + 4) = s1;
    } else {
#pragma unroll
      for (int a = 0; a < 8; a++)
        if (ibase + a < N_ITEMS) orow[a] = acc[a][bb] + ubias + ib[a];
    }
  }
}

extern "C" void kernel_launch(void* const* d_in, const int* in_sizes, int n_in,
                              void* d_out, int out_size, void* d_ws, size_t ws_size,
                              hipStream_t stream) {
  const float* user_emb  = (const float*)d_in[0];
  const float* item_emb  = (const float*)d_in[1];
  const float* user_bias = (const float*)d_in[2];
  const float* item_bias = (const float*)d_in[3];
  const float* pop_emb   = (const float*)d_in[4];
  const float* uW1 = (const float*)d_in[5];
  const float* ub1 = (const float*)d_in[6];
  const float* uW2 = (const float*)d_in[7];
  const float* ub2 = (const float*)d_in[8];
  const float* iW1 = (const float*)d_in[9];
  const float* ib1 = (const float*)d_in[10];
  const float* iW2 = (const float*)d_in[11];
  const float* ib2 = (const float*)d_in[12];
  const float* gW1 = (const float*)d_in[13];
  const float* gb1 = (const float*)d_in[14];
  const float* gW2 = (const float*)d_in[15];
  const float* gb2 = (const float*)d_in[16];
  const float* adj_vals = (const float*)d_in[17];
  const int* adj_rows = (const int*)d_in[18];
  const int* adj_cols = (const int*)d_in[19];
  const int* bins  = (const int*)d_in[20];
  const int* users = (const int*)d_in[21];
  float* out = (float*)d_out;

  // workspace layout (float offsets); total ~132.7 MB
  // rowptr spans [32800000, 32950001); uflag AFTER it.
  float* ws = (float*)d_ws;
  float* Oacc = ws;                    // 9,600,000
  float* bufA = ws + 9600000;          // 9,600,000
  float* bufB = ws + 19200000;         // 9,600,000 (gstage pre-spmm)
  uint2* epack = (uint2*)(ws + 28800000);      // 2,000,000 * 8B -> ends 32800000
  int* rowptr = (int*)(ws + 32800000);         // 150,001 ints -> ends 32950001
  int* uflag  = (int*)(ws + 32960000);         // 100,000 ints -> ends 33060000
  int* ucnt   = (int*)(ws + 33060000);         // 1 (uflag+100000: one memset)
  int* ulist  = (int*)(ws + 33061000);         // 256
  float* Ut   = ws + 33130000;                 // 65*256
  float* WT   = ws + 33150000;                 // 4,096 (uW1T)
  float* hp   = ws + 33160000;                 // 640
  float* pp1  = ws + 33161000;                 // 640
  int* bcur   = (int*)(ws + 33170000);         // 293
  uint2* gstage = (uint2*)bufB;
  // fp16 E-tables (19.2 MB = 4.8M floats each):
  __half* Eh0 = (__half*)bufA;                 // emb table; dead after spmm1
  __half* E1h = (__half*)(bufA + 4800000);     // layer1 out; dead after spmm2
  __half* E2h = (__half*)bufB;                 // layer2 out (gstage dead); dead after spmm3
  float* H1 = bufA + 6400000;                  // 3,200,000 (E1h dead by then)
  float* I  = bufB;                            // 3,200,000 (E2h dead by then)
  const float* uW1T = WT;

  hipMemsetAsync(bcur, 0, NB2 * sizeof(int), stream);
  hipMemsetAsync(uflag, 0, 100001 * sizeof(int), stream);  // covers uflag+ucnt
  k_cvt<<<9375, 256, 0, stream>>>(user_emb, item_emb, Eh0);
  k_bcount<<<P1_BLOCKS, 256, 0, stream>>>(adj_rows, bcur);
  k_bscan<<<1, 512, 0, stream>>>(bcur);
  k_p1<<<P1_BLOCKS, 256, 0, stream>>>(adj_rows, adj_cols, adj_vals, bcur, gstage);
  k_p2<<<NB2, 256, 0, stream>>>(bcur, gstage, epack, rowptr);
  k_flags<<<1, 256, 0, stream>>>(users, uflag, ulist, ucnt);

  k_spmm1<<<37500, 256, 0, stream>>>(rowptr, epack, user_emb, item_emb, Eh0, uflag, E1h, Oacc);
  k_spmm2h<<<37500, 256, 0, stream>>>(rowptr, epack, E1h, uflag, E2h, Oacc);
  k_spmm3h<<<12564, 256, 0, stream>>>(rowptr, epack, E2h, ulist, ucnt, Oacc);

  k_wt<<<16, 256, 0, stream>>>(uW1, WT);
  k_pw<<<1, 256, 0, stream>>>(pop_emb, gW1, iW1, hp, pp1);
  k_user<<<4, 64, 0, stream>>>(Oacc, users, user_bias, uW1T, ub1, uW2, ub2, Ut);
  k_gemm1z<<<391, 256, 0, stream>>>(Oacc, gW1, iW1, bins, hp, pp1, gb1, gW2, gb2, ib1, H1);
  k_gemm2<<<391, 256, 0, stream>>>(H1, iW2, ib2, I);
  k_scores<<<dim3(391, 2), 256, 0, stream>>>(I, Ut, item_bias, out);
}

// Round 6
// 505.612 us; speedup vs baseline: 1.3288x; 1.0970x over previous
//
#include <hip/hip_runtime.h>
#include <hip/hip_fp16.h>

#define N_USERS 100000
#define N_ITEMS 50000
#define N_NODES 150000
#define D 64
#define NNZ 2000000
#define BATCH 256
#define POP_BINS 10

// bucketed CSR params
#define BSH 9
#define NB2 293            // ceil(150000/512)
#define CAP 8192           // max edges per bucket (mean 6827, sigma ~82)
#define P1_EPB 4096        // edges per block in pass 1
#define P1_BLOCKS 489      // ceil(NNZ/P1_EPB)

#define ST_P 130           // I-tile LDS pad for transposed stages
#define MAXC 7             // deep-issue chunks (4 edges each): covers deg<=28

// ---------------- pass 1: bucket edges into strided gstage ------------------
// bcur starts zeroed; block claims per-bucket ranges with one atomic each.
__global__ __launch_bounds__(256) void k_p1(const int* __restrict__ rows,
                                            const int* __restrict__ cols,
                                            const float* __restrict__ vals,
                                            int* __restrict__ bcur,
                                            uint2* __restrict__ gstage) {
  __shared__ int cnt[NB2];
  __shared__ int gbase[NB2];
  int t = threadIdx.x;
  for (int i = t; i < NB2; i += 256) cnt[i] = 0;
  __syncthreads();
  int base = blockIdx.x * P1_EPB;
  // pass A: count buckets
  for (int i = 0; i < 16; i++) {
    int e = base + i * 256 + t;
    if (e < NNZ) atomicAdd(&cnt[rows[e] >> BSH], 1);
  }
  __syncthreads();
  for (int i = t; i < NB2; i += 256) {
    int c = cnt[i];
    gbase[i] = c ? atomicAdd(&bcur[i], c) : 0;
    cnt[i] = 0;
  }
  __syncthreads();
  // pass B: re-read (L2-hot) and scatter into bucket-strided staging
  for (int i = 0; i < 16; i++) {
    int e = base + i * 256 + t;
    if (e < NNZ) {
      int r = rows[e];
      int b = r >> BSH;
      int rank = atomicAdd(&cnt[b], 1);
      unsigned key = ((unsigned)(r & 511) << 18) | (unsigned)cols[e];
      gstage[(size_t)b * CAP + gbase[b] + rank] =
          make_uint2(key, __float_as_uint(vals[e]));
    }
  }
}

// ---------------- pass 2: per-bucket LDS counting sort ----------------------
// Compact epack base claimed from a global cursor; emits rowbeg/rowend.
__global__ __launch_bounds__(256) void k_p2(const int* __restrict__ bcur,
                                            const uint2* __restrict__ gstage,
                                            uint2* __restrict__ epack,
                                            int* __restrict__ rowbeg,
                                            int* __restrict__ rowend,
                                            int* __restrict__ gcursor) {
  __shared__ int cnt[512];
  __shared__ int off[512];
  __shared__ int s[256];
  __shared__ int gbs;
  __shared__ uint2 buf[CAP];
  int b = blockIdx.x, t = threadIdx.x;
  int n = bcur[b];
  const uint2* gs = gstage + (size_t)b * CAP;
  if (t == 0) gbs = atomicAdd(gcursor, n);
  cnt[t] = 0;
  cnt[t + 256] = 0;
  __syncthreads();
  for (int j = t; j < n; j += 256)
    atomicAdd(&cnt[gs[j].x >> 18], 1);
  __syncthreads();
  // scan 512 entries (each thread owns 2)
  int c0 = cnt[2 * t], c1 = cnt[2 * t + 1];
  s[t] = c0 + c1;
  __syncthreads();
  for (int o = 1; o < 256; o <<= 1) {
    int x = (t >= o) ? s[t - o] : 0;
    __syncthreads();
    s[t] += x;
    __syncthreads();
  }
  int ex = t ? s[t - 1] : 0;
  off[2 * t] = ex;
  off[2 * t + 1] = ex + c0;
  int base = gbs;
  int gr = (b << BSH) + 2 * t;
  if (gr < N_NODES) { rowbeg[gr] = base + ex; rowend[gr] = base + ex + c0; }
  if (gr + 1 < N_NODES) { rowbeg[gr + 1] = base + ex + c0; rowend[gr + 1] = base + ex + c0 + c1; }
  __syncthreads();
  for (int j = t; j < n; j += 256) {
    uint2 ed = gs[j];
    int lr = ed.x >> 18;
    int pos = atomicAdd(&off[lr], 1);
    buf[pos] = make_uint2(ed.x & 0x3FFFFu, ed.y);
  }
  __syncthreads();
  for (int j = t; j < n; j += 256) epack[base + j] = buf[j];
}

// ---------------- batch-user flags (bitmask) + unique list ------------------
__global__ __launch_bounds__(256) void k_flags(const int* __restrict__ users,
                                               int* __restrict__ uflag,
                                               int* __restrict__ ulist,
                                               int* __restrict__ ucnt) {
  int u = users[threadIdx.x];
  int old = atomicOr(&uflag[u >> 5], 1 << (u & 31));
  if (!((old >> (u & 31)) & 1)) {
    int p = atomicAdd(ucnt, 1);
    ulist[p] = u;
  }
}

// ---------------- emb -> fp16 combined table --------------------------------
__global__ __launch_bounds__(256) void k_cvt(const float* __restrict__ ue,
                                             const float* __restrict__ ie,
                                             __half* __restrict__ Eh) {
  int t = blockIdx.x * 256 + threadIdx.x;     // float4 index, < 2,400,000
  if (t >= 2400000) return;
  size_t fo = (size_t)t * 4;
  const float* src = (fo < (size_t)N_USERS * 64) ? ue + fo
                                                 : ie + (fo - (size_t)N_USERS * 64);
  float4 v = *(const float4*)src;
  __half2* dst = (__half2*)(Eh + fo);
  dst[0] = __floats2half2_rn(v.x, v.y);
  dst[1] = __floats2half2_rn(v.z, v.w);
}

// ============ deep-issue quarter-wave SPMM core =============================
// lane = 16*q + p. Chunk c = 4 edges {beg+4c .. beg+4c+3}; quarter q owns
// edge beg+4c+q; lane covers cols {4p..4p+3} via one 8B half4 gather.
// Phase 1 issues ALL descriptor loads, phase 2 ALL gathers (static-indexed
// register arrays + wave-uniform guards -> no scratch, all loads in flight),
// phase 3 FMAs. Intra-chunk padding clamps to end-1 (same lines, val=0).
#define SPMM_DEEP(TBL)                                                        \
  int n = end - beg;                                                          \
  int nc = (n + 3) >> 2;                                                      \
  if (nc > MAXC) nc = MAXC;                                                   \
  uint2 ed[MAXC];                                                             \
  _Pragma("unroll")                                                           \
  for (int c = 0; c < MAXC; c++) {                                            \
    if (c < nc) {                                                             \
      int jj = beg + 4 * c + q;                                               \
      int jc = jj < end ? jj : end - 1;                                       \
      ed[c] = epack[jc];                                                      \
    }                                                                         \
  }                                                                           \
  uint2 rg[MAXC]; float rv[MAXC];                                             \
  _Pragma("unroll")                                                           \
  for (int c = 0; c < MAXC; c++) {                                            \
    if (c < nc) {                                                             \
      int jj = beg + 4 * c + q;                                               \
      rv[c] = (jj < end) ? __uint_as_float(ed[c].y) : 0.f;                    \
      rg[c] = *(const uint2*)(TBL + (size_t)ed[c].x * 64 + 4 * p);            \
    }                                                                         \
  }                                                                           \
  float a0 = 0.f, a1 = 0.f, a2 = 0.f, a3 = 0.f;                               \
  _Pragma("unroll")                                                           \
  for (int c = 0; c < MAXC; c++) {                                            \
    if (c < nc) {                                                             \
      float2 lo = __half22float2(*(const __half2*)&rg[c].x);                  \
      float2 hi = __half22float2(*(const __half2*)&rg[c].y);                  \
      a0 += rv[c] * lo.x; a1 += rv[c] * lo.y;                                 \
      a2 += rv[c] * hi.x; a3 += rv[c] * hi.y;                                 \
    }                                                                         \
  }                                                                           \
  for (int j = beg + 4 * MAXC; j < end; j += 4) {  /* deg>28: ~1 row total */ \
    int jj = j + q;                                                           \
    int jc = jj < end ? jj : end - 1;                                         \
    uint2 e = epack[jc];                                                      \
    float v = (jj < end) ? __uint_as_float(e.y) : 0.f;                        \
    uint2 r = *(const uint2*)(TBL + (size_t)e.x * 64 + 4 * p);                \
    float2 lo = __half22float2(*(const __half2*)&r.x);                        \
    float2 hi = __half22float2(*(const __half2*)&r.y);                        \
    a0 += v * lo.x; a1 += v * lo.y; a2 += v * hi.x; a3 += v * hi.y;           \
  }                                                                           \
  a0 += __shfl_xor(a0, 16, 64); a0 += __shfl_xor(a0, 32, 64);                 \
  a1 += __shfl_xor(a1, 16, 64); a1 += __shfl_xor(a1, 32, 64);                 \
  a2 += __shfl_xor(a2, 16, 64); a2 += __shfl_xor(a2, 32, 64);                 \
  a3 += __shfl_xor(a3, 16, 64); a3 += __shfl_xor(a3, 32, 64);

// ---------------- SPMM layer 1 ----------------------------------------------
__global__ __launch_bounds__(256) void k_spmm1(const int* __restrict__ rowbeg,
                                               const int* __restrict__ rowend,
                                               const uint2* __restrict__ epack,
                                               const float* __restrict__ ue,
                                               const float* __restrict__ ie,
                                               const __half* __restrict__ Eh0,
                                               const int* __restrict__ uflag,
                                               __half* __restrict__ EoutH,
                                               float* __restrict__ Oacc) {
  int wave = blockIdx.x * 4 + (threadIdx.x >> 6);
  int row = __builtin_amdgcn_readfirstlane(wave);
  if (row >= N_NODES) return;
  int lane = threadIdx.x & 63;
  int p = lane & 15, q = lane >> 4;
  int beg = rowbeg[row];
  int end = rowend[row];
  SPMM_DEEP(Eh0)
  if (q == 0) {
    __half2* eo = (__half2*)(EoutH + (size_t)row * 64 + 4 * p);
    eo[0] = __floats2half2_rn(a0, a1);
    eo[1] = __floats2half2_rn(a2, a3);
    bool need = (row >= N_USERS) || (((uflag[row >> 5] >> (row & 31)) & 1) != 0);
    if (need) {
      const float* srow = (row < N_USERS) ? ue + (size_t)row * 64
                                          : ie + (size_t)(row - N_USERS) * 64;
      float4 sv = *(const float4*)(srow + 4 * p);
      *(float4*)(Oacc + (size_t)row * 64 + 4 * p) =
          make_float4(0.25f * (sv.x + a0), 0.25f * (sv.y + a1),
                      0.25f * (sv.z + a2), 0.25f * (sv.w + a3));
    }
  }
}

// ---------------- SPMM layer 2 ----------------------------------------------
__global__ __launch_bounds__(256) void k_spmm2h(const int* __restrict__ rowbeg,
                                                const int* __restrict__ rowend,
                                                const uint2* __restrict__ epack,
                                                const __half* __restrict__ Ein,
                                                const int* __restrict__ uflag,
                                                __half* __restrict__ EoutH,
                                                float* __restrict__ Oacc) {
  int wave = blockIdx.x * 4 + (threadIdx.x >> 6);
  int row = __builtin_amdgcn_readfirstlane(wave);
  if (row >= N_NODES) return;
  int lane = threadIdx.x & 63;
  int p = lane & 15, q = lane >> 4;
  int beg = rowbeg[row];
  int end = rowend[row];
  SPMM_DEEP(Ein)
  if (q == 0) {
    __half2* eo = (__half2*)(EoutH + (size_t)row * 64 + 4 * p);
    eo[0] = __floats2half2_rn(a0, a1);
    eo[1] = __floats2half2_rn(a2, a3);
    if (row >= N_USERS || (((uflag[row >> 5] >> (row & 31)) & 1) != 0)) {
      float4* op = (float4*)(Oacc + (size_t)row * 64 + 4 * p);
      float4 cur = *op;
      *op = make_float4(cur.x + 0.25f * a0, cur.y + 0.25f * a1,
                        cur.z + 0.25f * a2, cur.w + 0.25f * a3);
    }
  }
}

// ---------------- SPMM layer 3: only needed rows ----------------------------
__global__ __launch_bounds__(256) void k_spmm3h(const int* __restrict__ rowbeg,
                                                const int* __restrict__ rowend,
                                                const uint2* __restrict__ epack,
                                                const __half* __restrict__ Ein,
                                                const int* __restrict__ ulist,
                                                const int* __restrict__ ucnt,
                                                float* __restrict__ Oacc) {
  int w = blockIdx.x * 4 + (threadIdx.x >> 6);
  int row;
  if (w < N_ITEMS) {
    row = N_USERS + w;
  } else {
    int k = w - N_ITEMS;
    if (k >= ucnt[0]) return;
    row = ulist[k];
  }
  row = __builtin_amdgcn_readfirstlane(row);
  int lane = threadIdx.x & 63;
  int p = lane & 15, q = lane >> 4;
  int beg = rowbeg[row];
  int end = rowend[row];
  SPMM_DEEP(Ein)
  if (q == 0) {
    float4* op = (float4*)(Oacc + (size_t)row * 64 + 4 * p);
    float4 cur = *op;
    *op = make_float4(cur.x + 0.25f * a0, cur.y + 0.25f * a1,
                      cur.z + 0.25f * a2, cur.w + 0.25f * a3);
  }
}

// ---------------- pop-row precompute: hp[b]=p_b@gW1_p, pp1[b]=p_b@iW1 -------
__global__ __launch_bounds__(256) void k_pw(const float* __restrict__ pop,
                                            const float* __restrict__ gW1,
                                            const float* __restrict__ iW1,
                                            float* __restrict__ hp,
                                            float* __restrict__ pp1) {
  for (int idx = threadIdx.x; idx < 2 * POP_BINS * 64; idx += 256) {
    int q = idx;
    bool second = q >= POP_BINS * 64;
    if (second) q -= POP_BINS * 64;
    int b = q >> 6, o = q & 63;
    float s = 0.f;
    if (!second) {
      for (int k = 0; k < 64; k++) s += pop[b * 64 + k] * gW1[(64 + k) * 64 + o];
      hp[q] = s;
    } else {
      for (int k = 0; k < 64; k++) s += pop[b * 64 + k] * iW1[k * 64 + o];
      pp1[q] = s;
    }
  }
}

// ---------------- user MLP: one wave per user, coalesced weights ------------
// lane o: h[o] = relu(ub1[o] + sum_k x[k]*uW1[k*64+o]); x[k] via lane
// broadcast. No transpose kernel needed; weights L2-resident across waves.
__global__ __launch_bounds__(256) void k_user(const float* __restrict__ Oacc,
                                              const int* __restrict__ users,
                                              const float* __restrict__ ubias,
                                              const float* __restrict__ uW1,
                                              const float* __restrict__ ub1,
                                              const float* __restrict__ uW2,
                                              const float* __restrict__ ub2,
                                              float* __restrict__ Ut) {
  int ub = blockIdx.x * 4 + (threadIdx.x >> 6);
  int lane = threadIdx.x & 63;
  int u = users[ub];
  float x = Oacc[(size_t)u * 64 + lane];
  float h = ub1[lane];
#pragma unroll
  for (int k = 0; k < 64; k++)
    h = fmaf(__shfl(x, k, 64), uW1[k * 64 + lane], h);
  h = h > 0.f ? h : 0.f;
  float o = ub2[lane];
#pragma unroll
  for (int k = 0; k < 64; k++)
    o = fmaf(__shfl(h, k, 64), uW2[k * 64 + lane], o);
  Ut[lane * 256 + ub] = o;
  if (lane == 0) Ut[64 * 256 + ub] = ubias[u];  // BIAS_SCALE = 1.0
}

// ---------------- GEMM1 fused with gate (G|T in regs -> z -> H1) ------------
__global__ __launch_bounds__(256) void k_gemm1z(const float* __restrict__ Oacc,
                                                const float* __restrict__ gW1,
                                                const float* __restrict__ iW1,
                                                const int* __restrict__ bins,
                                                const float* __restrict__ hp,
                                                const float* __restrict__ pp1,
                                                const float* __restrict__ gb1,
                                                const float* __restrict__ gW2,
                                                const float* __restrict__ gb2,
                                                const float* __restrict__ ib1,
                                                float* __restrict__ H1) {
  __shared__ float Is[64 * ST_P];
  __shared__ float Bs[64 * 128];
  __shared__ float zp[128][9];   // z partials, padded
  __shared__ float zs[128];      // final z per item
  int tid = threadIdx.x;
  int i0 = blockIdx.x * 128;
  {
    int c4 = tid & 15, r0 = tid >> 4;
#pragma unroll
    for (int s = 0; s < 8; s++) {
      int r = r0 + s * 16;
      int it = i0 + r;
      float4 v = make_float4(0.f, 0.f, 0.f, 0.f);
      if (it < N_ITEMS) v = *(const float4*)(Oacc + (size_t)(N_USERS + it) * 64 + c4 * 4);
      Is[(c4 * 4 + 0) * ST_P + r] = v.x;
      Is[(c4 * 4 + 1) * ST_P + r] = v.y;
      Is[(c4 * 4 + 2) * ST_P + r] = v.z;
      Is[(c4 * 4 + 3) * ST_P + r] = v.w;
    }
  }
  for (int idx = tid; idx < 64 * 128; idx += 256) {
    int k = idx >> 7, o = idx & 127;
    Bs[idx] = (o < 64) ? gW1[k * 64 + o] : iW1[k * 64 + (o - 64)];
  }
  __syncthreads();
  int tx = tid & 15, ty = tid >> 4;
  float acc[8][8];
#pragma unroll
  for (int a = 0; a < 8; a++)
#pragma unroll
    for (int b = 0; b < 8; b++) acc[a][b] = 0.f;
  const float* ip = Is + tx * 8;
  const float* wp = Bs + ty * 8;
#pragma unroll 2
  for (int k = 0; k < 64; k++) {
    float4 iv0 = *(const float4*)(ip + k * ST_P);
    float4 iv1 = *(const float4*)(ip + k * ST_P + 4);
    float4 wv0 = *(const float4*)(wp + k * 128);
    float4 wv1 = *(const float4*)(wp + k * 128 + 4);
    float iv[8] = {iv0.x, iv0.y, iv0.z, iv0.w, iv1.x, iv1.y, iv1.z, iv1.w};
    float wv[8] = {wv0.x, wv0.y, wv0.z, wv0.w, wv1.x, wv1.y, wv1.z, wv1.w};
#pragma unroll
    for (int a = 0; a < 8; a++)
#pragma unroll
      for (int b = 0; b < 8; b++) acc[a][b] += iv[a] * wv[b];
  }
  int ibase = i0 + tx * 8;
  // --- gate epilogue ---
  if (ty < 8) {  // G half: z partials over this thread's 8 o-columns
    int o0 = ty * 8;
#pragma unroll
    for (int a = 0; a < 8; a++) {
      int it = ibase + a;
      float p = 0.f;
      if (it < N_ITEMS) {
        int bin = bins[it];
        const float* hpr = hp + bin * 64 + o0;
#pragma unroll
        for (int b = 0; b < 8; b++) {
          float g = acc[a][b] + hpr[b] + gb1[o0 + b];
          g = g > 0.f ? g : 0.f;
          p += g * gW2[o0 + b];
        }
      }
      zp[tx * 8 + a][ty] = p;
    }
  }
  __syncthreads();
  if (tid < 128) {
    float s = gb2[0];
#pragma unroll
    for (int k = 0; k < 8; k++) s += zp[tid][k];
    zs[tid] = 1.f / (1.f + expf(-s));
  }
  __syncthreads();
  if (ty >= 8) {  // T half: fuse + relu -> H1
    int o0 = (ty - 8) * 8;
#pragma unroll
    for (int a = 0; a < 8; a++) {
      int it = ibase + a;
      if (it < N_ITEMS) {
        float z = zs[tx * 8 + a];
        int bin = bins[it];
        const float* ppr = pp1 + bin * 64 + o0;
        float h[8];
#pragma unroll
        for (int b = 0; b < 8; b++) {
          float v = (1.f - z) * acc[a][b] + z * ppr[b] + ib1[o0 + b];
          h[b] = v > 0.f ? v : 0.f;
        }
        *(float4*)(H1 + (size_t)it * 64 + o0) = make_float4(h[0], h[1], h[2], h[3]);
        *(float4*)(H1 + (size_t)it * 64 + o0 + 4) = make_float4(h[4], h[5], h[6], h[7]);
      }
    }
  }
}

// ---------------- GEMM2: I = H1 @ iW2 + ib2  (128x64 tile, K=64) ------------
__global__ __launch_bounds__(256) void k_gemm2(const float* __restrict__ H1,
                                               const float* __restrict__ iW2,
                                               const float* __restrict__ ib2,
                                               float* __restrict__ I) {
  __shared__ float Is[64 * ST_P];
  __shared__ float Bs[64 * 64];
  int tid = threadIdx.x;
  int i0 = blockIdx.x * 128;
  {
    int c4 = tid & 15, r0 = tid >> 4;
#pragma unroll
    for (int s = 0; s < 8; s++) {
      int r = r0 + s * 16;
      int it = i0 + r;
      float4 v = make_float4(0.f, 0.f, 0.f, 0.f);
      if (it < N_ITEMS) v = *(const float4*)(H1 + (size_t)it * 64 + c4 * 4);
      Is[(c4 * 4 + 0) * ST_P + r] = v.x;
      Is[(c4 * 4 + 1) * ST_P + r] = v.y;
      Is[(c4 * 4 + 2) * ST_P + r] = v.z;
      Is[(c4 * 4 + 3) * ST_P + r] = v.w;
    }
  }
  for (int idx = tid; idx < 64 * 64; idx += 256) Bs[idx] = iW2[idx];
  __syncthreads();
  int tx = tid & 15, ty = tid >> 4;
  float acc[8][4];
#pragma unroll
  for (int a = 0; a < 8; a++)
#pragma unroll
    for (int b = 0; b < 4; b++) acc[a][b] = 0.f;
  const float* ip = Is + tx * 8;
  const float* wp = Bs + ty * 4;
#pragma unroll 2
  for (int k = 0; k < 64; k++) {
    float4 iv0 = *(const float4*)(ip + k * ST_P);
    float4 iv1 = *(const float4*)(ip + k * ST_P + 4);
    float4 wv = *(const float4*)(wp + k * 64);
    float iv[8] = {iv0.x, iv0.y, iv0.z, iv0.w, iv1.x, iv1.y, iv1.z, iv1.w};
    float wvv[4] = {wv.x, wv.y, wv.z, wv.w};
#pragma unroll
    for (int a = 0; a < 8; a++)
#pragma unroll
      for (int b = 0; b < 4; b++) acc[a][b] += iv[a] * wvv[b];
  }
  int ibase = i0 + tx * 8;
  int oc = ty * 4;
  float b0 = ib2[oc], b1 = ib2[oc + 1], b2 = ib2[oc + 2], b3 = ib2[oc + 3];
#pragma unroll
  for (int a = 0; a < 8; a++) {
    int it = ibase + a;
    if (it < N_ITEMS) {
      float4 s0 = make_float4(acc[a][0] + b0, acc[a][1] + b1,
                              acc[a][2] + b2, acc[a][3] + b3);
      *(float4*)(I + (size_t)it * 64 + oc) = s0;
    }
  }
}

// ---------------- scores: 128x128 tile GEMM, 8x8 register blocking ----------
__global__ __launch_bounds__(256) void k_scores(const float* __restrict__ I,
                                                const float* __restrict__ Ut,
                                                const float* __restrict__ item_bias,
                                                float* __restrict__ out) {
  __shared__ float Is[64 * ST_P];
  __shared__ float Us[64 * 128];
  int tid = threadIdx.x;
  int i0 = blockIdx.x * 128;
  int ubase = blockIdx.y * 128;
  {
    int c4 = tid & 15, r0 = tid >> 4;
#pragma unroll
    for (int s = 0; s < 8; s++) {
      int r = r0 + s * 16;
      int it = i0 + r;
      float4 v = make_float4(0.f, 0.f, 0.f, 0.f);
      if (it < N_ITEMS) v = *(const float4*)(I + (size_t)it * 64 + c4 * 4);
      Is[(c4 * 4 + 0) * ST_P + r] = v.x;
      Is[(c4 * 4 + 1) * ST_P + r] = v.y;
      Is[(c4 * 4 + 2) * ST_P + r] = v.z;
      Is[(c4 * 4 + 3) * ST_P + r] = v.w;
    }
  }
  {
    int u4 = tid & 31, k0 = tid >> 5;
#pragma unroll
    for (int s = 0; s < 8; s++) {
      int k = k0 + s * 8;
      float4 v = *(const float4*)(Ut + k * 256 + ubase + u4 * 4);
      *(float4*)(Us + k * 128 + u4 * 4) = v;
    }
  }
  __syncthreads();
  int tx = tid & 15;
  int ty = tid >> 4;
  float acc[8][8];
#pragma unroll
  for (int a = 0; a < 8; a++)
#pragma unroll
    for (int b = 0; b < 8; b++) acc[a][b] = 0.f;
  const float* ip = Is + tx * 8;
  const float* up = Us + ty * 8;
#pragma unroll 2
  for (int k = 0; k < 64; k++) {
    float4 iv0 = *(const float4*)(ip + k * ST_P);
    float4 iv1 = *(const float4*)(ip + k * ST_P + 4);
    float4 uv0 = *(const float4*)(up + k * 128);
    float4 uv1 = *(const float4*)(up + k * 128 + 4);
    float iv[8] = {iv0.x, iv0.y, iv0.z, iv0.w, iv1.x, iv1.y, iv1.z, iv1.w};
    float uv[8] = {uv0.x, uv0.y, uv0.z, uv0.w, uv1.x, uv1.y, uv1.z, uv1.w};
#pragma unroll
    for (int a = 0; a < 8; a++)
#pragma unroll
      for (int b = 0; b < 8; b++) acc[a][b] += iv[a] * uv[b];
  }
  int ibase = i0 + tx * 8;
  float ib[8];
#pragma unroll
  for (int a = 0; a < 8; a++)
    ib[a] = (ibase + a < N_ITEMS) ? item_bias[ibase + a] : 0.f;
#pragma unroll
  for (int bb = 0; bb < 8; bb++) {
    int bu = ubase + ty * 8 + bb;
    float ubias = Ut[64 * 256 + bu];
    float* orow = out + (size_t)bu * N_ITEMS + ibase;
    if (ibase + 7 < N_ITEMS) {
      float4 s0 = make_float4(acc[0][bb] + ubias + ib[0], acc[1][bb] + ubias + ib[1],
                              acc[2][bb] + ubias + ib[2], acc[3][bb] + ubias + ib[3]);
      float4 s1 = make_float4(acc[4][bb] + ubias + ib[4], acc[5][bb] + ubias + ib[5],
                              acc[6][bb] + ubias + ib[6], acc[7][bb] + ubias + ib[7]);
      *(float4*)orow = s0;
      *(float4*)(orow + 4) = s1;
    } else {
#pragma unroll
      for (int a = 0; a < 8; a++)
        if (ibase + a < N_ITEMS) orow[a] = acc[a][bb] + ubias + ib[a];
    }
  }
}

extern "C" void kernel_launch(void* const* d_in, const int* in_sizes, int n_in,
                              void* d_out, int out_size, void* d_ws, size_t ws_size,
                              hipStream_t stream) {
  const float* user_emb  = (const float*)d_in[0];
  const float* item_emb  = (const float*)d_in[1];
  const float* user_bias = (const float*)d_in[2];
  const float* item_bias = (const float*)d_in[3];
  const float* pop_emb   = (const float*)d_in[4];
  const float* uW1 = (const float*)d_in[5];
  const float* ub1 = (const float*)d_in[6];
  const float* uW2 = (const float*)d_in[7];
  const float* ub2 = (const float*)d_in[8];
  const float* iW1 = (const float*)d_in[9];
  const float* ib1 = (const float*)d_in[10];
  const float* iW2 = (const float*)d_in[11];
  const float* ib2 = (const float*)d_in[12];
  const float* gW1 = (const float*)d_in[13];
  const float* gb1 = (const float*)d_in[14];
  const float* gW2 = (const float*)d_in[15];
  const float* gb2 = (const float*)d_in[16];
  const float* adj_vals = (const float*)d_in[17];
  const int* adj_rows = (const int*)d_in[18];
  const int* adj_cols = (const int*)d_in[19];
  const int* bins  = (const int*)d_in[20];
  const int* users = (const int*)d_in[21];
  float* out = (float*)d_out;

  // workspace layout (float offsets); high-water 33,123,294 < previous 33,170,293
  float* ws = (float*)d_ws;
  float* Oacc = ws;                    // 9,600,000
  float* bufA = ws + 9600000;          // 9,600,000
  float* bufB = ws + 19200000;         // 9,600,000 (strided gstage: 4,800,512)
  uint2* epack = (uint2*)(ws + 28800000);      // 2M uint2 -> ends 32,800,000
  int* rowbeg = (int*)(ws + 32800000);         // 150,000 -> 32,950,000
  int* rowend = (int*)(ws + 32950000);         // 150,000 -> 33,100,000
  int* uflag  = (int*)(ws + 33100000);         // 3,125 (bitmask) -> 33,103,125
  int* ucnt   = (int*)(ws + 33103125);         // 1 (adjacent: one memset)
  int* ulist  = (int*)(ws + 33103130);         // 256
  float* Ut   = ws + 33104000;                 // 16,640 -> 33,120,640
  float* hp   = ws + 33121000;                 // 640
  float* pp1  = ws + 33122000;                 // 640
  int* bcur   = (int*)(ws + 33123000);         // 293
  int* gcursor = (int*)(ws + 33123293);        // 1 (adjacent: one memset)
  uint2* gstage = (uint2*)bufB;                // 293*8192*8B = 19.2 MB
  // fp16 E-tables (19.2 MB each):
  __half* Eh0 = (__half*)bufA;                 // emb table; dead after spmm1
  __half* E1h = (__half*)(bufA + 4800000);     // layer1 out; dead after spmm2
  __half* E2h = (__half*)bufB;                 // layer2 out (gstage dead)
  float* H1 = bufA + 6400000;                  // 3,200,000 (E1h dead by then)
  float* I  = bufB;                            // 3,200,000 (E2h dead by then)

  hipMemsetAsync(bcur, 0, 294 * sizeof(int), stream);     // bcur + gcursor
  hipMemsetAsync(uflag, 0, 3126 * sizeof(int), stream);   // uflag + ucnt
  k_cvt<<<9375, 256, 0, stream>>>(user_emb, item_emb, Eh0);
  k_p1<<<P1_BLOCKS, 256, 0, stream>>>(adj_rows, adj_cols, adj_vals, bcur, gstage);
  k_p2<<<NB2, 256, 0, stream>>>(bcur, gstage, epack, rowbeg, rowend, gcursor);
  k_flags<<<1, 256, 0, stream>>>(users, uflag, ulist, ucnt);

  k_spmm1<<<37500, 256, 0, stream>>>(rowbeg, rowend, epack, user_emb, item_emb, Eh0, uflag, E1h, Oacc);
  k_spmm2h<<<37500, 256, 0, stream>>>(rowbeg, rowend, epack, E1h, uflag, E2h, Oacc);
  k_spmm3h<<<12564, 256, 0, stream>>>(rowbeg, rowend, epack, E2h, ulist, ucnt, Oacc);

  k_pw<<<1, 256, 0, stream>>>(pop_emb, gW1, iW1, hp, pp1);
  k_user<<<64, 256, 0, stream>>>(Oacc, users, user_bias, uW1, ub1, uW2, ub2, Ut);
  k_gemm1z<<<391, 256, 0, stream>>>(Oacc, gW1, iW1, bins, hp, pp1, gb1, gW2, gb2, ib1, H1);
  k_gemm2<<<391, 256, 0, stream>>>(H1, iW2, ib2, I);
  k_scores<<<dim3(391, 2), 256, 0, stream>>>(I, Ut, item_bias, out);
}

// Round 7
// 476.447 us; speedup vs baseline: 1.4101x; 1.0612x over previous
//
#include <hip/hip_runtime.h>
#include <hip/hip_fp16.h>

#define N_USERS 100000
#define N_ITEMS 50000
#define N_NODES 150000
#define D 64
#define NNZ 2000000
#define BATCH 256
#define POP_BINS 10

// bucketed CSR params
#define BSH 9
#define NB2 293            // ceil(150000/512)
#define CAP 8192           // max edges per bucket (mean 6827, sigma ~82)
#define P1_EPB 4096        // edges per block in pass 1
#define P1_BLOCKS 489      // ceil(NNZ/P1_EPB)

#define ST_P 130           // I-tile LDS pad for transposed stages

// ---------------- pass 1: bucket edges into strided gstage ------------------
__global__ __launch_bounds__(256) void k_p1(const int* __restrict__ rows,
                                            const int* __restrict__ cols,
                                            const float* __restrict__ vals,
                                            int* __restrict__ bcur,
                                            uint2* __restrict__ gstage) {
  __shared__ int cnt[NB2];
  __shared__ int gbase[NB2];
  int t = threadIdx.x;
  for (int i = t; i < NB2; i += 256) cnt[i] = 0;
  __syncthreads();
  int base = blockIdx.x * P1_EPB;
  for (int i = 0; i < 16; i++) {
    int e = base + i * 256 + t;
    if (e < NNZ) atomicAdd(&cnt[rows[e] >> BSH], 1);
  }
  __syncthreads();
  for (int i = t; i < NB2; i += 256) {
    int c = cnt[i];
    gbase[i] = c ? atomicAdd(&bcur[i], c) : 0;
    cnt[i] = 0;
  }
  __syncthreads();
  for (int i = 0; i < 16; i++) {
    int e = base + i * 256 + t;
    if (e < NNZ) {
      int r = rows[e];
      int b = r >> BSH;
      int rank = atomicAdd(&cnt[b], 1);
      unsigned key = ((unsigned)(r & 511) << 18) | (unsigned)cols[e];
      gstage[(size_t)b * CAP + gbase[b] + rank] =
          make_uint2(key, __float_as_uint(vals[e]));
    }
  }
}

// ---------------- pass 2 (+batch flags at b==NB2) ---------------------------
__global__ __launch_bounds__(256) void k_p2(const int* __restrict__ bcur,
                                            const uint2* __restrict__ gstage,
                                            uint2* __restrict__ epack,
                                            int* __restrict__ rowbeg,
                                            int* __restrict__ rowend,
                                            int* __restrict__ gcursor,
                                            const int* __restrict__ users,
                                            int* __restrict__ uflag,
                                            int* __restrict__ ulist,
                                            int* __restrict__ ucnt) {
  int b = blockIdx.x, t = threadIdx.x;
  if (b == NB2) {  // batch-user flags (bitmask) + unique list
    int u = users[t];
    int old = atomicOr(&uflag[u >> 5], 1 << (u & 31));
    if (!((old >> (u & 31)) & 1)) {
      int p = atomicAdd(ucnt, 1);
      ulist[p] = u;
    }
    return;
  }
  __shared__ int cnt[512];
  __shared__ int off[512];
  __shared__ int s[256];
  __shared__ int gbs;
  __shared__ uint2 buf[CAP];
  int n = bcur[b];
  const uint2* gs = gstage + (size_t)b * CAP;
  if (t == 0) gbs = atomicAdd(gcursor, n);
  cnt[t] = 0;
  cnt[t + 256] = 0;
  __syncthreads();
  for (int j = t; j < n; j += 256)
    atomicAdd(&cnt[gs[j].x >> 18], 1);
  __syncthreads();
  int c0 = cnt[2 * t], c1 = cnt[2 * t + 1];
  s[t] = c0 + c1;
  __syncthreads();
  for (int o = 1; o < 256; o <<= 1) {
    int x = (t >= o) ? s[t - o] : 0;
    __syncthreads();
    s[t] += x;
    __syncthreads();
  }
  int ex = t ? s[t - 1] : 0;
  off[2 * t] = ex;
  off[2 * t + 1] = ex + c0;
  int base = gbs;
  int gr = (b << BSH) + 2 * t;
  if (gr < N_NODES) { rowbeg[gr] = base + ex; rowend[gr] = base + ex + c0; }
  if (gr + 1 < N_NODES) { rowbeg[gr + 1] = base + ex + c0; rowend[gr + 1] = base + ex + c0 + c1; }
  __syncthreads();
  for (int j = t; j < n; j += 256) {
    uint2 ed = gs[j];
    int lr = ed.x >> 18;
    int pos = atomicAdd(&off[lr], 1);
    buf[pos] = make_uint2(ed.x & 0x3FFFFu, ed.y);
  }
  __syncthreads();
  for (int j = t; j < n; j += 256) epack[base + j] = buf[j];
}

// ---------------- prep: emb->fp16 table (blocks 0..9374) + pop rows (9375) --
__global__ __launch_bounds__(256) void k_prep(const float* __restrict__ ue,
                                              const float* __restrict__ ie,
                                              __half* __restrict__ Eh,
                                              const float* __restrict__ pop,
                                              const float* __restrict__ gW1,
                                              const float* __restrict__ iW1,
                                              float* __restrict__ hp,
                                              float* __restrict__ pp1) {
  int b = blockIdx.x;
  if (b == 9375) {  // hp[b]=p_b@gW1_pop, pp1[b]=p_b@iW1
    for (int idx = threadIdx.x; idx < 2 * POP_BINS * 64; idx += 256) {
      int q = idx;
      bool second = q >= POP_BINS * 64;
      if (second) q -= POP_BINS * 64;
      int bb = q >> 6, o = q & 63;
      float s = 0.f;
      if (!second) {
        for (int k = 0; k < 64; k++) s += pop[bb * 64 + k] * gW1[(64 + k) * 64 + o];
        hp[q] = s;
      } else {
        for (int k = 0; k < 64; k++) s += pop[bb * 64 + k] * iW1[k * 64 + o];
        pp1[q] = s;
      }
    }
    return;
  }
  int t = b * 256 + threadIdx.x;     // float4 index, < 2,400,000
  size_t fo = (size_t)t * 4;
  const float* src = (fo < (size_t)N_USERS * 64) ? ue + fo
                                                 : ie + (fo - (size_t)N_USERS * 64);
  float4 v = *(const float4*)src;
  __half2* dst = (__half2*)(Eh + fo);
  dst[0] = __floats2half2_rn(v.x, v.y);
  dst[1] = __floats2half2_rn(v.z, v.w);
}

// ============ quarter-wave SPMM core (round-5 body: measured fastest) =======
// lane = 16*q + p. Quarter q owns edge j+q; lane covers cols {4p..4p+3} via
// one 8B half4 gather. One wave request = 4 edges. Tail clamps to end-1
// (same lines as last valid quarter, val=0).
#define SPMM_QW_BODY(TBL)                                                     \
  float a0 = 0.f, a1 = 0.f, a2 = 0.f, a3 = 0.f;                               \
  int j = beg;                                                                \
  for (; j + 7 < end; j += 8) {                                               \
    uint2 ea = epack[j + q];                                                  \
    uint2 eb = epack[j + 4 + q];                                              \
    uint2 ra = *(const uint2*)(TBL + (size_t)ea.x * 64 + 4 * p);              \
    uint2 rb = *(const uint2*)(TBL + (size_t)eb.x * 64 + 4 * p);              \
    float va = __uint_as_float(ea.y), vb = __uint_as_float(eb.y);             \
    float2 la = __half22float2(*(const __half2*)&ra.x);                       \
    float2 ha = __half22float2(*(const __half2*)&ra.y);                       \
    float2 lb = __half22float2(*(const __half2*)&rb.x);                       \
    float2 hb = __half22float2(*(const __half2*)&rb.y);                       \
    a0 += va * la.x; a1 += va * la.y; a2 += va * ha.x; a3 += va * ha.y;       \
    a0 += vb * lb.x; a1 += vb * lb.y; a2 += vb * hb.x; a3 += vb * hb.y;       \
  }                                                                           \
  for (; j < end; j += 4) {                                                   \
    int jj = j + q;                                                           \
    int jc = (jj < end) ? jj : end - 1;                                       \
    uint2 e = epack[jc];                                                      \
    float v = (jj < end) ? __uint_as_float(e.y) : 0.f;                        \
    uint2 r = *(const uint2*)(TBL + (size_t)e.x * 64 + 4 * p);                \
    float2 lo = __half22float2(*(const __half2*)&r.x);                        \
    float2 hi = __half22float2(*(const __half2*)&r.y);                        \
    a0 += v * lo.x; a1 += v * lo.y; a2 += v * hi.x; a3 += v * hi.y;           \
  }                                                                           \
  a0 += __shfl_xor(a0, 16, 64); a0 += __shfl_xor(a0, 32, 64);                 \
  a1 += __shfl_xor(a1, 16, 64); a1 += __shfl_xor(a1, 32, 64);                 \
  a2 += __shfl_xor(a2, 16, 64); a2 += __shfl_xor(a2, 32, 64);                 \
  a3 += __shfl_xor(a3, 16, 64); a3 += __shfl_xor(a3, 32, 64);

// ---------------- SPMM layer 1 ----------------------------------------------
__global__ __launch_bounds__(256) void k_spmm1(const int* __restrict__ rowbeg,
                                               const int* __restrict__ rowend,
                                               const uint2* __restrict__ epack,
                                               const float* __restrict__ ue,
                                               const float* __restrict__ ie,
                                               const __half* __restrict__ Eh0,
                                               const int* __restrict__ uflag,
                                               __half* __restrict__ EoutH,
                                               float* __restrict__ Oacc) {
  int wave = blockIdx.x * 4 + (threadIdx.x >> 6);
  int row = __builtin_amdgcn_readfirstlane(wave);
  if (row >= N_NODES) return;
  int lane = threadIdx.x & 63;
  int p = lane & 15, q = lane >> 4;
  int beg = rowbeg[row];
  int end = rowend[row];
  SPMM_QW_BODY(Eh0)
  if (q == 0) {
    __half2* eo = (__half2*)(EoutH + (size_t)row * 64 + 4 * p);
    eo[0] = __floats2half2_rn(a0, a1);
    eo[1] = __floats2half2_rn(a2, a3);
    bool need = (row >= N_USERS) || (((uflag[row >> 5] >> (row & 31)) & 1) != 0);
    if (need) {
      const float* srow = (row < N_USERS) ? ue + (size_t)row * 64
                                          : ie + (size_t)(row - N_USERS) * 64;
      float4 sv = *(const float4*)(srow + 4 * p);
      *(float4*)(Oacc + (size_t)row * 64 + 4 * p) =
          make_float4(0.25f * (sv.x + a0), 0.25f * (sv.y + a1),
                      0.25f * (sv.z + a2), 0.25f * (sv.w + a3));
    }
  }
}

// ---------------- SPMM layer 2 ----------------------------------------------
__global__ __launch_bounds__(256) void k_spmm2h(const int* __restrict__ rowbeg,
                                                const int* __restrict__ rowend,
                                                const uint2* __restrict__ epack,
                                                const __half* __restrict__ Ein,
                                                const int* __restrict__ uflag,
                                                __half* __restrict__ EoutH,
                                                float* __restrict__ Oacc) {
  int wave = blockIdx.x * 4 + (threadIdx.x >> 6);
  int row = __builtin_amdgcn_readfirstlane(wave);
  if (row >= N_NODES) return;
  int lane = threadIdx.x & 63;
  int p = lane & 15, q = lane >> 4;
  int beg = rowbeg[row];
  int end = rowend[row];
  SPMM_QW_BODY(Ein)
  if (q == 0) {
    __half2* eo = (__half2*)(EoutH + (size_t)row * 64 + 4 * p);
    eo[0] = __floats2half2_rn(a0, a1);
    eo[1] = __floats2half2_rn(a2, a3);
    if (row >= N_USERS || (((uflag[row >> 5] >> (row & 31)) & 1) != 0)) {
      float4* op = (float4*)(Oacc + (size_t)row * 64 + 4 * p);
      float4 cur = *op;
      *op = make_float4(cur.x + 0.25f * a0, cur.y + 0.25f * a1,
                        cur.z + 0.25f * a2, cur.w + 0.25f * a3);
    }
  }
}

// ---------------- SPMM layer 3: only needed rows ----------------------------
__global__ __launch_bounds__(256) void k_spmm3h(const int* __restrict__ rowbeg,
                                                const int* __restrict__ rowend,
                                                const uint2* __restrict__ epack,
                                                const __half* __restrict__ Ein,
                                                const int* __restrict__ ulist,
                                                const int* __restrict__ ucnt,
                                                float* __restrict__ Oacc) {
  int w = blockIdx.x * 4 + (threadIdx.x >> 6);
  int row;
  if (w < N_ITEMS) {
    row = N_USERS + w;
  } else {
    int k = w - N_ITEMS;
    if (k >= ucnt[0]) return;
    row = ulist[k];
  }
  row = __builtin_amdgcn_readfirstlane(row);
  int lane = threadIdx.x & 63;
  int p = lane & 15, q = lane >> 4;
  int beg = rowbeg[row];
  int end = rowend[row];
  SPMM_QW_BODY(Ein)
  if (q == 0) {
    float4* op = (float4*)(Oacc + (size_t)row * 64 + 4 * p);
    float4 cur = *op;
    *op = make_float4(cur.x + 0.25f * a0, cur.y + 0.25f * a1,
                      cur.z + 0.25f * a2, cur.w + 0.25f * a3);
  }
}

// ---------------- user MLP: one wave per user, coalesced weights ------------
__global__ __launch_bounds__(256) void k_user(const float* __restrict__ Oacc,
                                              const int* __restrict__ users,
                                              const float* __restrict__ ubias,
                                              const float* __restrict__ uW1,
                                              const float* __restrict__ ub1,
                                              const float* __restrict__ uW2,
                                              const float* __restrict__ ub2,
                                              float* __restrict__ Ut) {
  int ub = blockIdx.x * 4 + (threadIdx.x >> 6);
  int lane = threadIdx.x & 63;
  int u = users[ub];
  float x = Oacc[(size_t)u * 64 + lane];
  float h = ub1[lane];
#pragma unroll
  for (int k = 0; k < 64; k++)
    h = fmaf(__shfl(x, k, 64), uW1[k * 64 + lane], h);
  h = h > 0.f ? h : 0.f;
  float o = ub2[lane];
#pragma unroll
  for (int k = 0; k < 64; k++)
    o = fmaf(__shfl(h, k, 64), uW2[k * 64 + lane], o);
  Ut[lane * 256 + ub] = o;
  if (lane == 0) Ut[64 * 256 + ub] = ubias[u];  // BIAS_SCALE = 1.0
}

// ---------------- GEMM1+gate+GEMM2 fused: Oacc -> I  ------------------------
// Stage 1: [G|T] = X@[gW1|iW1] in regs; z via LDS; H1 kept in LDS (reuse Is);
// stage 2: I = H1 @ iW2 + ib2 in-block. H1 never touches global.
__global__ __launch_bounds__(256) void k_gemm12(const float* __restrict__ Oacc,
                                                const float* __restrict__ gW1,
                                                const float* __restrict__ iW1,
                                                const int* __restrict__ bins,
                                                const float* __restrict__ hp,
                                                const float* __restrict__ pp1,
                                                const float* __restrict__ gb1,
                                                const float* __restrict__ gW2,
                                                const float* __restrict__ gb2,
                                                const float* __restrict__ ib1,
                                                const float* __restrict__ iW2,
                                                const float* __restrict__ ib2,
                                                float* __restrict__ I) {
  __shared__ float Is[64 * ST_P];   // X^T, then H1^T after the z-sync
  __shared__ float Bs[64 * 128];    // [gW1|iW1], then iW2 in first 4096
  __shared__ float zp[128][9];
  __shared__ float zs[128];
  int tid = threadIdx.x;
  int i0 = blockIdx.x * 128;
  {
    int c4 = tid & 15, r0 = tid >> 4;
#pragma unroll
    for (int s = 0; s < 8; s++) {
      int r = r0 + s * 16;
      int it = i0 + r;
      float4 v = make_float4(0.f, 0.f, 0.f, 0.f);
      if (it < N_ITEMS) v = *(const float4*)(Oacc + (size_t)(N_USERS + it) * 64 + c4 * 4);
      Is[(c4 * 4 + 0) * ST_P + r] = v.x;
      Is[(c4 * 4 + 1) * ST_P + r] = v.y;
      Is[(c4 * 4 + 2) * ST_P + r] = v.z;
      Is[(c4 * 4 + 3) * ST_P + r] = v.w;
    }
  }
  for (int idx = tid; idx < 64 * 128; idx += 256) {
    int k = idx >> 7, o = idx & 127;
    Bs[idx] = (o < 64) ? gW1[k * 64 + o] : iW1[k * 64 + (o - 64)];
  }
  __syncthreads();
  int tx = tid & 15, ty = tid >> 4;
  float acc[8][8];
#pragma unroll
  for (int a = 0; a < 8; a++)
#pragma unroll
    for (int b = 0; b < 8; b++) acc[a][b] = 0.f;
  {
    const float* ip = Is + tx * 8;
    const float* wp = Bs + ty * 8;
#pragma unroll 2
    for (int k = 0; k < 64; k++) {
      float4 iv0 = *(const float4*)(ip + k * ST_P);
      float4 iv1 = *(const float4*)(ip + k * ST_P + 4);
      float4 wv0 = *(const float4*)(wp + k * 128);
      float4 wv1 = *(const float4*)(wp + k * 128 + 4);
      float iv[8] = {iv0.x, iv0.y, iv0.z, iv0.w, iv1.x, iv1.y, iv1.z, iv1.w};
      float wv[8] = {wv0.x, wv0.y, wv0.z, wv0.w, wv1.x, wv1.y, wv1.z, wv1.w};
#pragma unroll
      for (int a = 0; a < 8; a++)
#pragma unroll
        for (int b = 0; b < 8; b++) acc[a][b] += iv[a] * wv[b];
    }
  }
  int ibase = i0 + tx * 8;
  // --- gate: z partials from G half ---
  if (ty < 8) {
    int o0 = ty * 8;
#pragma unroll
    for (int a = 0; a < 8; a++) {
      int it = ibase + a;
      float p = 0.f;
      if (it < N_ITEMS) {
        int bin = bins[it];
        const float* hpr = hp + bin * 64 + o0;
#pragma unroll
        for (int b = 0; b < 8; b++) {
          float g = acc[a][b] + hpr[b] + gb1[o0 + b];
          g = g > 0.f ? g : 0.f;
          p += g * gW2[o0 + b];
        }
      }
      zp[tx * 8 + a][ty] = p;
    }
  }
  __syncthreads();   // also: everyone done reading Is/Bs
  if (tid < 128) {
    float s = gb2[0];
#pragma unroll
    for (int k = 0; k < 8; k++) s += zp[tid][k];
    zs[tid] = 1.f / (1.f + expf(-s));
  }
  __syncthreads();
  // --- T half: H1 -> LDS (reuse Is, layout [col][item]); stage iW2 -> Bs ---
  if (ty >= 8) {
    int o0 = (ty - 8) * 8;
#pragma unroll
    for (int a = 0; a < 8; a++) {
      int it = ibase + a;
      int item = tx * 8 + a;
      float z = zs[item];
      int bin = (it < N_ITEMS) ? bins[it] : 0;
      const float* ppr = pp1 + bin * 64 + o0;
#pragma unroll
      for (int b = 0; b < 8; b++) {
        float v = (1.f - z) * acc[a][b] + z * ppr[b] + ib1[o0 + b];
        Is[(o0 + b) * ST_P + item] = v > 0.f ? v : 0.f;
      }
    }
  }
  for (int idx = tid; idx < 64 * 64; idx += 256) Bs[idx] = iW2[idx];
  __syncthreads();
  // --- stage 2: I = H1 @ iW2 + ib2 (128x64, K=64) ---
  float acc2[8][4];
#pragma unroll
  for (int a = 0; a < 8; a++)
#pragma unroll
    for (int b = 0; b < 4; b++) acc2[a][b] = 0.f;
  {
    const float* ip = Is + tx * 8;
    const float* wp = Bs + ty * 4;
#pragma unroll 2
    for (int k = 0; k < 64; k++) {
      float4 iv0 = *(const float4*)(ip + k * ST_P);
      float4 iv1 = *(const float4*)(ip + k * ST_P + 4);
      float4 wv = *(const float4*)(wp + k * 64);
      float iv[8] = {iv0.x, iv0.y, iv0.z, iv0.w, iv1.x, iv1.y, iv1.z, iv1.w};
      float wvv[4] = {wv.x, wv.y, wv.z, wv.w};
#pragma unroll
      for (int a = 0; a < 8; a++)
#pragma unroll
        for (int b = 0; b < 4; b++) acc2[a][b] += iv[a] * wvv[b];
    }
  }
  int oc = ty * 4;
  float b0 = ib2[oc], b1 = ib2[oc + 1], b2 = ib2[oc + 2], b3 = ib2[oc + 3];
#pragma unroll
  for (int a = 0; a < 8; a++) {
    int it = ibase + a;
    if (it < N_ITEMS) {
      float4 s0 = make_float4(acc2[a][0] + b0, acc2[a][1] + b1,
                              acc2[a][2] + b2, acc2[a][3] + b3);
      *(float4*)(I + (size_t)it * 64 + oc) = s0;
    }
  }
}

// ---------------- scores: Is staged once, both user-halves per block --------
__global__ __launch_bounds__(256) void k_scores(const float* __restrict__ I,
                                                const float* __restrict__ Ut,
                                                const float* __restrict__ item_bias,
                                                float* __restrict__ out) {
  __shared__ float Is[64 * ST_P];
  __shared__ float Us[64 * 128];
  int tid = threadIdx.x;
  int i0 = blockIdx.x * 128;
  {
    int c4 = tid & 15, r0 = tid >> 4;
#pragma unroll
    for (int s = 0; s < 8; s++) {
      int r = r0 + s * 16;
      int it = i0 + r;
      float4 v = make_float4(0.f, 0.f, 0.f, 0.f);
      if (it < N_ITEMS) v = *(const float4*)(I + (size_t)it * 64 + c4 * 4);
      Is[(c4 * 4 + 0) * ST_P + r] = v.x;
      Is[(c4 * 4 + 1) * ST_P + r] = v.y;
      Is[(c4 * 4 + 2) * ST_P + r] = v.z;
      Is[(c4 * 4 + 3) * ST_P + r] = v.w;
    }
  }
  int tx = tid & 15;
  int ty = tid >> 4;
  int ibase = i0 + tx * 8;
  float ib[8];
#pragma unroll
  for (int a = 0; a < 8; a++)
    ib[a] = (ibase + a < N_ITEMS) ? item_bias[ibase + a] : 0.f;
  for (int uh = 0; uh < 2; uh++) {
    int ubase = uh * 128;
    if (uh) __syncthreads();   // previous Us fully consumed
    {
      int u4 = tid & 31, k0 = tid >> 5;
#pragma unroll
      for (int s = 0; s < 8; s++) {
        int k = k0 + s * 8;
        float4 v = *(const float4*)(Ut + k * 256 + ubase + u4 * 4);
        *(float4*)(Us + k * 128 + u4 * 4) = v;
      }
    }
    __syncthreads();
    float acc[8][8];
#pragma unroll
    for (int a = 0; a < 8; a++)
#pragma unroll
      for (int b = 0; b < 8; b++) acc[a][b] = 0.f;
    const float* ip = Is + tx * 8;
    const float* up = Us + ty * 8;
#pragma unroll 2
    for (int k = 0; k < 64; k++) {
      float4 iv0 = *(const float4*)(ip + k * ST_P);
      float4 iv1 = *(const float4*)(ip + k * ST_P + 4);
      float4 uv0 = *(const float4*)(up + k * 128);
      float4 uv1 = *(const float4*)(up + k * 128 + 4);
      float iv[8] = {iv0.x, iv0.y, iv0.z, iv0.w, iv1.x, iv1.y, iv1.z, iv1.w};
      float uv[8] = {uv0.x, uv0.y, uv0.z, uv0.w, uv1.x, uv1.y, uv1.z, uv1.w};
#pragma unroll
      for (int a = 0; a < 8; a++)
#pragma unroll
        for (int b = 0; b < 8; b++) acc[a][b] += iv[a] * uv[b];
    }
#pragma unroll
    for (int bb = 0; bb < 8; bb++) {
      int bu = ubase + ty * 8 + bb;
      float ubias = Ut[64 * 256 + bu];
      float* orow = out + (size_t)bu * N_ITEMS + ibase;
      if (ibase + 7 < N_ITEMS) {
        float4 s0 = make_float4(acc[0][bb] + ubias + ib[0], acc[1][bb] + ubias + ib[1],
                                acc[2][bb] + ubias + ib[2], acc[3][bb] + ubias + ib[3]);
        float4 s1 = make_float4(acc[4][bb] + ubias + ib[4], acc[5][bb] + ubias + ib[5],
                                acc[6][bb] + ubias + ib[6], acc[7][bb] + ubias + ib[7]);
        *(float4*)orow = s0;
        *(float4*)(orow + 4) = s1;
      } else {
#pragma unroll
        for (int a = 0; a < 8; a++)
          if (ibase + a < N_ITEMS) orow[a] = acc[a][bb] + ubias + ib[a];
      }
    }
  }
}

extern "C" void kernel_launch(void* const* d_in, const int* in_sizes, int n_in,
                              void* d_out, int out_size, void* d_ws, size_t ws_size,
                              hipStream_t stream) {
  const float* user_emb  = (const float*)d_in[0];
  const float* item_emb  = (const float*)d_in[1];
  const float* user_bias = (const float*)d_in[2];
  const float* item_bias = (const float*)d_in[3];
  const float* pop_emb   = (const float*)d_in[4];
  const float* uW1 = (const float*)d_in[5];
  const float* ub1 = (const float*)d_in[6];
  const float* uW2 = (const float*)d_in[7];
  const float* ub2 = (const float*)d_in[8];
  const float* iW1 = (const float*)d_in[9];
  const float* ib1 = (const float*)d_in[10];
  const float* iW2 = (const float*)d_in[11];
  const float* ib2 = (const float*)d_in[12];
  const float* gW1 = (const float*)d_in[13];
  const float* gb1 = (const float*)d_in[14];
  const float* gW2 = (const float*)d_in[15];
  const float* gb2 = (const float*)d_in[16];
  const float* adj_vals = (const float*)d_in[17];
  const int* adj_rows = (const int*)d_in[18];
  const int* adj_cols = (const int*)d_in[19];
  const int* bins  = (const int*)d_in[20];
  const int* users = (const int*)d_in[21];
  float* out = (float*)d_out;

  // workspace layout (float offsets); high-water 33,122,640
  float* ws = (float*)d_ws;
  float* Oacc = ws;                    // 9,600,000
  float* bufA = ws + 9600000;          // 9,600,000
  float* bufB = ws + 19200000;         // 9,600,000 (strided gstage)
  uint2* epack = (uint2*)(ws + 28800000);      // 2M uint2 -> ends 32,800,000
  int* rowbeg = (int*)(ws + 32800000);         // 150,000 -> 32,950,000
  int* rowend = (int*)(ws + 32950000);         // 150,000 -> 33,100,000
  // control ints: contiguous for a single memset
  int* uflag   = (int*)(ws + 33100000);        // 3,125 (bitmask)
  int* ucnt    = (int*)(ws + 33103125);        // 1
  int* bcur    = (int*)(ws + 33103126);        // 293
  int* gcursor = (int*)(ws + 33103419);        // 1
  int* ulist   = (int*)(ws + 33103420);        // 256 -> ends 33,103,676
  float* Ut   = ws + 33104000;                 // 16,640 -> 33,120,640
  float* hp   = ws + 33121000;                 // 640
  float* pp1  = ws + 33122000;                 // 640
  uint2* gstage = (uint2*)bufB;                // 293*8192*8B = 19.2 MB
  __half* Eh0 = (__half*)bufA;                 // emb fp16; dead after spmm1
  __half* E1h = (__half*)(bufA + 4800000);     // layer1 out; dead after spmm2
  __half* E2h = (__half*)bufB;                 // layer2 out (gstage dead)
  float* I  = bufB;                            // 3,200,000 (E2h dead by then)

  hipMemsetAsync(uflag, 0, 3680 * sizeof(int), stream);  // uflag..ulist
  k_prep<<<9376, 256, 0, stream>>>(user_emb, item_emb, Eh0, pop_emb, gW1, iW1, hp, pp1);
  k_p1<<<P1_BLOCKS, 256, 0, stream>>>(adj_rows, adj_cols, adj_vals, bcur, gstage);
  k_p2<<<NB2 + 1, 256, 0, stream>>>(bcur, gstage, epack, rowbeg, rowend, gcursor,
                                    users, uflag, ulist, ucnt);

  k_spmm1<<<37500, 256, 0, stream>>>(rowbeg, rowend, epack, user_emb, item_emb,
                                     Eh0, uflag, E1h, Oacc);
  k_spmm2h<<<37500, 256, 0, stream>>>(rowbeg, rowend, epack, E1h, uflag, E2h, Oacc);
  k_spmm3h<<<12564, 256, 0, stream>>>(rowbeg, rowend, epack, E2h, ulist, ucnt, Oacc);

  k_user<<<64, 256, 0, stream>>>(Oacc, users, user_bias, uW1, ub1, uW2, ub2, Ut);
  k_gemm12<<<391, 256, 0, stream>>>(Oacc, gW1, iW1, bins, hp, pp1, gb1, gW2, gb2,
                                    ib1, iW2, ib2, I);
  k_scores<<<391, 256, 0, stream>>>(I, Ut, item_bias, out);
}